// Round 13
// baseline (15566.501 us; speedup 1.0000x reference)
//
#include <hip/hip_runtime.h>

// ---------------------------------------------------------------------------
// MultiLayerNormGRU on MI355X (gfx950) — round 13.
// Persistent point-to-point pipeline (NO grid.sync, NO cooperative launch):
// one 192-block dispatch, all blocks co-resident (1 block/CU, 64 CU slack).
//   blocks   0- 31 : L0 recurrence, all chunks (weights in AGPR/LDS once)
//   blocks  32- 63 : L1 recurrence, all chunks
//   blocks  64-127 : A — precomp P0 (x @ Wx0, K=64) into 4-deep ring
//   blocks 128-191 : C — precomp P1 (h0 @ Wx1, K=256) into 4-deep ring
// Handoffs via device-scope atomic counters + agent fences (Guideline 16):
//   A(k) waits fL0[k-R];  L0(k) waits fP0[k]==64 & fP1[k-R]==64 (h0 slot free)
//   C(k) waits fL0[k]==32 & fL1[k-R];  L1(k) waits fP1[k]==64.
// Step body = R7/R12 (shfl-LN + 1-step P prefetch), measured s~4.4us/step.
// ---------------------------------------------------------------------------

#define B_   512
#define T_   512
#define DIN  64
#define H_   256
#define OUT_ 64
#define EPS_ 1e-5f

typedef __attribute__((ext_vector_type(8))) short bf16x8;
typedef __attribute__((ext_vector_type(4))) float f32x4;

__device__ __forceinline__ unsigned short f2bf(float f) {
  unsigned int u = __float_as_uint(f);
  u += 0x7fffu + ((u >> 16) & 1u);          // RNE f32 -> bf16
  return (unsigned short)(u >> 16);
}
__device__ __forceinline__ float bfh(unsigned short u) {
  return __uint_as_float(((unsigned int)u) << 16);
}
__device__ __forceinline__ float sigm_(float x) {
  return __builtin_amdgcn_rcpf(1.f + __expf(-x));
}
__device__ __forceinline__ float tanh_(float x) {
  return 1.f - 2.f * __builtin_amdgcn_rcpf(__expf(2.f * x) + 1.f);
}
template<int C>
__device__ __forceinline__ float dpp_add(float v) {
  int r = __builtin_amdgcn_update_dpp(0, __float_as_int(v), C, 0xF, 0xF, false);
  return v + __int_as_float(r);
}
__device__ __forceinline__ float red16(float v) {  // sum over 16-lane row
  v = dpp_add<0x121>(v);
  v = dpp_add<0x122>(v);
  v = dpp_add<0x124>(v);
  v = dpp_add<0x128>(v);
  return v;
}

#define PIN8A(a) asm volatile("" : "+a"(a[0]), "+a"(a[1]), "+a"(a[2]), "+a"(a[3]), \
                                   "+a"(a[4]), "+a"(a[5]), "+a"(a[6]), "+a"(a[7]))

// ------------------------- flag sync primitives ------------------------------
__device__ __forceinline__ void waitflag(int* f, int val) {
  if (threadIdx.x == 0) {
    while (__hip_atomic_load(f, __ATOMIC_ACQUIRE, __HIP_MEMORY_SCOPE_AGENT) < val)
      __builtin_amdgcn_s_sleep(8);
    __threadfence();
  }
  __syncthreads();
}
__device__ __forceinline__ void postflag(int* f) {
  __syncthreads();
  __threadfence();
  if (threadIdx.x == 0)
    __hip_atomic_fetch_add(f, 1, __ATOMIC_RELEASE, __HIP_MEMORY_SCOPE_AGENT);
}

__global__ void zero_flags(int* f) {
  if (threadIdx.x < 512) f[threadIdx.x] = 0;
}

// ------------------------- prep kernels --------------------------------------
__global__ void prep_frag(const float* __restrict__ w, unsigned short* __restrict__ dst,
                          int N, int Ksrc, int koff) {
  int gid = blockIdx.x * 256 + threadIdx.x;
  if (gid >= N * 256) return;
  int n = gid >> 8, k = gid & 255;
  int idx = (((n >> 4) * 8 + (k >> 5)) * 64 + ((n & 15) + 16 * ((k >> 3) & 3))) * 8 + (k & 7);
  dst[idx] = f2bf(w[(size_t)n * Ksrc + koff + k]);
}

__global__ void prep_wx(const float* __restrict__ wg, const float* __restrict__ wc,
                        unsigned short* __restrict__ dst, int KX, int Kg, int Kc) {
  int gid = blockIdx.x * 256 + threadIdx.x;
  if (gid >= 768 * KX) return;
  int n = gid / KX, k = gid - n * KX;
  float v = (n < 512) ? wg[(size_t)n * Kg + k] : wc[(size_t)(n - 512) * Kc + k];
  dst[gid] = f2bf(v);
}

__global__ void bias_cat(const float* __restrict__ bg, const float* __restrict__ bc,
                         float* __restrict__ dst) {
  int i = blockIdx.x * 256 + threadIdx.x;
  if (i < 768) dst[i] = (i < 512) ? bg[i] : bc[i - 512];
}

// ------------------------- precomp tile (256-thread team) --------------------
__device__ __forceinline__ void precomp_tile(
    const void* __restrict__ Asrc, const unsigned short* __restrict__ wx,
    const float* __restrict__ bias, unsigned short* __restrict__ Pc,
    int TC, int t0, int KX, int AFP32,
    int mi, int nb, unsigned short* A_s, unsigned short* B_s, int t256)
{
  const int lane = t256 & 63, wv = t256 >> 6;     // wv 0..3
  const int m0 = mi * 128;
  const int bt = m0 / (TC * 16);
  const int tt0 = (m0 - bt * TC * 16) >> 4;
  const int mq = wv >> 1, nq = wv & 1;
  const int crow0 = (lane >> 4) * 4;

  f32x4 acc[4][4];
#pragma unroll
  for (int i = 0; i < 4; ++i)
#pragma unroll
    for (int j = 0; j < 4; ++j) acc[i][j] = (f32x4){0, 0, 0, 0};

  for (int kb = 0; kb < (KX >> 6); ++kb) {
    __syncthreads();
#pragma unroll
    for (int it = 0; it < 4; ++it) {
      int s = t256 + it * 256;
      int rg = s >> 3, k8 = s & 7;
      int mt = rg >> 4, r15 = rg & 15;
      int dl = r15 + 16 * (k8 & 3), kc = k8 >> 2;
      if (AFP32) {
        const float* xp = (const float*)Asrc +
            (((size_t)(bt * 16 + r15)) * T_ + (t0 + tt0 + mt)) * DIN + kb * 64 + k8 * 8;
        float4 u0 = *(const float4*)xp, u1 = *(const float4*)(xp + 4);
        unsigned short tmp[8];
        tmp[0] = f2bf(u0.x); tmp[1] = f2bf(u0.y); tmp[2] = f2bf(u0.z); tmp[3] = f2bf(u0.w);
        tmp[4] = f2bf(u1.x); tmp[5] = f2bf(u1.y); tmp[6] = f2bf(u1.z); tmp[7] = f2bf(u1.w);
        *reinterpret_cast<bf16x8*>(&A_s[((mt * 2 + kc) * 64 + dl) * 8]) =
            *reinterpret_cast<bf16x8*>(tmp);
      } else {
        const unsigned short* ap = (const unsigned short*)Asrc +
            ((size_t)(m0 + rg)) * KX + kb * 64 + k8 * 8;
        *reinterpret_cast<bf16x8*>(&A_s[((mt * 2 + kc) * 64 + dl) * 8]) =
            *reinterpret_cast<const bf16x8*>(ap);
      }
      const unsigned short* bp = wx + ((size_t)(nb + rg)) * KX + kb * 64 + k8 * 8;
      *reinterpret_cast<bf16x8*>(&B_s[((mt * 2 + kc) * 64 + dl) * 8]) =
          *reinterpret_cast<const bf16x8*>(bp);
    }
    __syncthreads();
#pragma unroll
    for (int kc = 0; kc < 2; ++kc) {
      bf16x8 av[4], bv[4];
#pragma unroll
      for (int i = 0; i < 4; ++i) {
        av[i] = *reinterpret_cast<const bf16x8*>(&A_s[(((mq * 4 + i) * 2 + kc) * 64 + lane) * 8]);
        bv[i] = *reinterpret_cast<const bf16x8*>(&B_s[(((nq * 4 + i) * 2 + kc) * 64 + lane) * 8]);
      }
#pragma unroll
      for (int i = 0; i < 4; ++i)
#pragma unroll
        for (int j = 0; j < 4; ++j)
          acc[i][j] = __builtin_amdgcn_mfma_f32_16x16x32_bf16(av[i], bv[j], acc[i][j], 0, 0, 0);
    }
  }
  float bb[4];
#pragma unroll
  for (int j = 0; j < 4; ++j) bb[j] = bias[nb + nq * 64 + j * 16 + (lane & 15)];
#pragma unroll
  for (int i = 0; i < 4; ++i) {
    int tt = tt0 + mq * 4 + i;
#pragma unroll
    for (int j = 0; j < 4; ++j) {
      int n = nb + nq * 64 + j * 16 + (lane & 15);
      ushort4 o;
      o.x = f2bf(acc[i][j][0] + bb[j]); o.y = f2bf(acc[i][j][1] + bb[j]);
      o.z = f2bf(acc[i][j][2] + bb[j]); o.w = f2bf(acc[i][j][3] + bb[j]);
      *reinterpret_cast<ushort4*>(&Pc[((size_t)(bt * TC + tt) * 768 + n) * 16 + crow0]) = o;
    }
  }
}

// ------------------------- gru pieces (R7/R12 body) --------------------------
struct GP {
  float gw_r0, gb_r0, gw_r1, gb_r1;
  float gw_z0, gb_z0, gw_z1, gb_z1;
  float cw0, cb0, cw1, cb1;
};

__device__ __forceinline__ void gru_init(
    unsigned char* smem,
    const unsigned short* __restrict__ gfrag,
    const unsigned short* __restrict__ cfrag,
    const float* __restrict__ gnw, const float* __restrict__ gnb,
    const float* __restrict__ cnw, const float* __restrict__ cnb,
    bf16x8 (&wgr0)[8], bf16x8 (&wgr1)[8], bf16x8 (&wgr2)[8], bf16x8 (&wgr3)[8],
    GP& p, float (&hm)[2][4])
{
  unsigned short* wc_s = (unsigned short*)smem;
  unsigned short (*h_s)[264] = (unsigned short(*)[264])(smem + 131072);
  const int tid = threadIdx.x, lane = tid & 63, wv = tid >> 6;
  const int colr0 = 32 * wv + (lane & 15), colr1 = colr0 + 16;
  const int nt0 = 2 * wv, nt1 = 2 * wv + 1, nt2 = 16 + 2 * wv, nt3 = 17 + 2 * wv;

  for (int i = tid; i < 8192; i += 512)
    *reinterpret_cast<bf16x8*>(&wc_s[i * 8]) = *reinterpret_cast<const bf16x8*>(&cfrag[i * 8]);
#pragma unroll
  for (int kc = 0; kc < 8; ++kc) {
    wgr0[kc] = *reinterpret_cast<const bf16x8*>(&gfrag[((nt0 * 8 + kc) * 64 + lane) * 8]);
    wgr1[kc] = *reinterpret_cast<const bf16x8*>(&gfrag[((nt1 * 8 + kc) * 64 + lane) * 8]);
    wgr2[kc] = *reinterpret_cast<const bf16x8*>(&gfrag[((nt2 * 8 + kc) * 64 + lane) * 8]);
    wgr3[kc] = *reinterpret_cast<const bf16x8*>(&gfrag[((nt3 * 8 + kc) * 64 + lane) * 8]);
  }
  p.gw_r0 = gnw[colr0];       p.gb_r0 = gnb[colr0];
  p.gw_r1 = gnw[colr1];       p.gb_r1 = gnb[colr1];
  p.gw_z0 = gnw[256 + colr0]; p.gb_z0 = gnb[256 + colr0];
  p.gw_z1 = gnw[256 + colr1]; p.gb_z1 = gnb[256 + colr1];
  p.cw0 = cnw[colr0]; p.cb0 = cnb[colr0];
  p.cw1 = cnw[colr1]; p.cb1 = cnb[colr1];
#pragma unroll
  for (int g = 0; g < 4; ++g) { hm[0][g] = 0.f; hm[1][g] = 0.f; }
  for (int i = tid; i < 16 * 264; i += 512) (&h_s[0][0])[i] = 0;
  __syncthreads();
}

__device__ __forceinline__ void gru_chunk(
    unsigned char* smem, int bt,
    bf16x8 (&wgr0)[8], bf16x8 (&wgr1)[8], bf16x8 (&wgr2)[8], bf16x8 (&wgr3)[8],
    const GP& p, float (&hm)[2][4],
    const unsigned short* __restrict__ Pc,
    unsigned short* __restrict__ h0out,
    int TC)
{
  unsigned short* wc_s = (unsigned short*)smem;
  unsigned short (*h_s)[264]  = (unsigned short(*)[264])(smem + 131072);
  unsigned short (*rh_s)[264] = (unsigned short(*)[264])(smem + 139520);
  float (*sumP)[20] = (float(*)[20])(smem + 147968);
  float (*sqP)[20]  = (float(*)[20])(smem + 148608);

  const int tid = threadIdx.x, lane = tid & 63, wv = tid >> 6;
  const int arow = lane & 15, koff = (lane >> 4) * 8, crow0 = (lane >> 4) * 4;
  const int colr0 = 32 * wv + (lane & 15), colr1 = colr0 + 16;
  const int nt0 = 2 * wv, nt1 = 2 * wv + 1;

  const unsigned short* Pr = Pc + ((size_t)bt * TC * 768 + colr0) * 16;
  // prefetch step 0
  ushort4 npr0 = *reinterpret_cast<const ushort4*>(Pr + crow0);
  ushort4 npr1 = *reinterpret_cast<const ushort4*>(Pr + 256 + crow0);
  ushort4 npz0 = *reinterpret_cast<const ushort4*>(Pr + 4096 + crow0);
  ushort4 npz1 = *reinterpret_cast<const ushort4*>(Pr + 4352 + crow0);
  ushort4 npn0 = *reinterpret_cast<const ushort4*>(Pr + 8192 + crow0);
  ushort4 npn1 = *reinterpret_cast<const ushort4*>(Pr + 8448 + crow0);

  for (int tt = 0; tt < TC; ++tt) {
    PIN8A(wgr0); PIN8A(wgr1); PIN8A(wgr2); PIN8A(wgr3);

    ushort4 pr0 = npr0, pr1 = npr1, pz0 = npz0, pz1 = npz1, pn0 = npn0, pn1 = npn1;
    if (tt + 1 < TC) {
      Pr += 12288;
      npr0 = *reinterpret_cast<const ushort4*>(Pr + crow0);
      npr1 = *reinterpret_cast<const ushort4*>(Pr + 256 + crow0);
      npz0 = *reinterpret_cast<const ushort4*>(Pr + 4096 + crow0);
      npz1 = *reinterpret_cast<const ushort4*>(Pr + 4352 + crow0);
      npn0 = *reinterpret_cast<const ushort4*>(Pr + 8192 + crow0);
      npn1 = *reinterpret_cast<const ushort4*>(Pr + 8448 + crow0);
    }

    // ---- gates MFMA (AGPR weights) ----
    f32x4 a0 = {0, 0, 0, 0}, a1 = {0, 0, 0, 0}, a2 = {0, 0, 0, 0}, a3 = {0, 0, 0, 0};
#pragma unroll
    for (int kc = 0; kc < 8; ++kc) {
      bf16x8 av = *reinterpret_cast<const bf16x8*>(&h_s[arow][kc * 32 + koff]);
      a0 = __builtin_amdgcn_mfma_f32_16x16x32_bf16(av, wgr0[kc], a0, 0, 0, 0);
      a1 = __builtin_amdgcn_mfma_f32_16x16x32_bf16(av, wgr1[kc], a1, 0, 0, 0);
      a2 = __builtin_amdgcn_mfma_f32_16x16x32_bf16(av, wgr2[kc], a2, 0, 0, 0);
      a3 = __builtin_amdgcn_mfma_f32_16x16x32_bf16(av, wgr3[kc], a3, 0, 0, 0);
    }
    float vr0[4], vr1[4], vz0[4], vz1[4];
    {
      float s4[4], q4[4];
#pragma unroll
      for (int g = 0; g < 4; ++g) {
        vr0[g] = a0[g] + bfh(((const unsigned short*)&pr0)[g]);
        vr1[g] = a1[g] + bfh(((const unsigned short*)&pr1)[g]);
        vz0[g] = a2[g] + bfh(((const unsigned short*)&pz0)[g]);
        vz1[g] = a3[g] + bfh(((const unsigned short*)&pz1)[g]);
        s4[g] = red16(vr0[g] + vr1[g] + vz0[g] + vz1[g]);
        q4[g] = red16(vr0[g] * vr0[g] + vr1[g] * vr1[g] + vz0[g] * vz0[g] + vz1[g] * vz1[g]);
      }
      if ((lane & 15) == 0) {
        *reinterpret_cast<f32x4*>(&sumP[wv][crow0]) = (f32x4){s4[0], s4[1], s4[2], s4[3]};
        *reinterpret_cast<f32x4*>(&sqP[wv][crow0])  = (f32x4){q4[0], q4[1], q4[2], q4[3]};
      }
    }
    __syncthreads();                                   // B1

    // ---- gate LN stats (shfl broadcast) + apply ----
    float zf[2][4];
    {
      int sg = lane >> 4, rr = lane & 15;
      float S = sumP[2 * sg][rr] + sumP[2 * sg + 1][rr];
      float Q = sqP[2 * sg][rr] + sqP[2 * sg + 1][rr];
      S += __shfl_xor(S, 16, 64); Q += __shfl_xor(Q, 16, 64);
      S += __shfl_xor(S, 32, 64); Q += __shfl_xor(Q, 32, 64);
      float mn = S * (1.f / 512.f);
      float rs = __builtin_amdgcn_rsqf(Q * (1.f / 512.f) - mn * mn + EPS_);
#pragma unroll
      for (int g = 0; g < 4; ++g) {
        float m_ = __shfl(mn, crow0 + g, 64);
        float r_ = __shfl(rs, crow0 + g, 64);
        float rv0 = sigm_(fmaf((vr0[g] - m_) * r_, p.gw_r0, p.gb_r0));
        float rv1 = sigm_(fmaf((vr1[g] - m_) * r_, p.gw_r1, p.gb_r1));
        zf[0][g]  = sigm_(fmaf((vz0[g] - m_) * r_, p.gw_z0, p.gb_z0));
        zf[1][g]  = sigm_(fmaf((vz1[g] - m_) * r_, p.gw_z1, p.gb_z1));
        rh_s[crow0 + g][colr0] = f2bf(rv0 * hm[0][g]);
        rh_s[crow0 + g][colr1] = f2bf(rv1 * hm[1][g]);
      }
    }
    __syncthreads();                                   // B2

    // ---- cand MFMA (LDS weights) ----
    f32x4 c0a = {0, 0, 0, 0}, c1a = {0, 0, 0, 0};
#pragma unroll
    for (int kc = 0; kc < 8; ++kc) {
      bf16x8 av = *reinterpret_cast<const bf16x8*>(&rh_s[arow][kc * 32 + koff]);
      bf16x8 b0v = *reinterpret_cast<const bf16x8*>(&wc_s[((nt0 * 8 + kc) * 64 + lane) * 8]);
      bf16x8 b1v = *reinterpret_cast<const bf16x8*>(&wc_s[((nt1 * 8 + kc) * 64 + lane) * 8]);
      c0a = __builtin_amdgcn_mfma_f32_16x16x32_bf16(av, b0v, c0a, 0, 0, 0);
      c1a = __builtin_amdgcn_mfma_f32_16x16x32_bf16(av, b1v, c1a, 0, 0, 0);
    }
    float vc0[4], vc1[4];
    {
      float s4[4], q4[4];
#pragma unroll
      for (int g = 0; g < 4; ++g) {
        vc0[g] = c0a[g] + bfh(((const unsigned short*)&pn0)[g]);
        vc1[g] = c1a[g] + bfh(((const unsigned short*)&pn1)[g]);
        s4[g] = red16(vc0[g] + vc1[g]);
        q4[g] = red16(vc0[g] * vc0[g] + vc1[g] * vc1[g]);
      }
      if ((lane & 15) == 0) {
        *reinterpret_cast<f32x4*>(&sumP[wv][crow0]) = (f32x4){s4[0], s4[1], s4[2], s4[3]};
        *reinterpret_cast<f32x4*>(&sqP[wv][crow0])  = (f32x4){q4[0], q4[1], q4[2], q4[3]};
      }
    }
    __syncthreads();                                   // B3

    // ---- cand LN (shfl broadcast) + tanh + h update ----
    {
      int sg = lane >> 4, rr = lane & 15;
      float S = sumP[2 * sg][rr] + sumP[2 * sg + 1][rr];
      float Q = sqP[2 * sg][rr] + sqP[2 * sg + 1][rr];
      S += __shfl_xor(S, 16, 64); Q += __shfl_xor(Q, 16, 64);
      S += __shfl_xor(S, 32, 64); Q += __shfl_xor(Q, 32, 64);
      float mn = S * (1.f / 256.f);
      float rs = __builtin_amdgcn_rsqf(Q * (1.f / 256.f) - mn * mn + EPS_);
      unsigned short* hrow = h0out ? (h0out + (size_t)(bt * TC + tt) * 4096) : (unsigned short*)nullptr;
#pragma unroll
      for (int g = 0; g < 4; ++g) {
        float m_ = __shfl(mn, crow0 + g, 64);
        float r_ = __shfl(rs, crow0 + g, 64);
        float n0 = tanh_(fmaf((vc0[g] - m_) * r_, p.cw0, p.cb0));
        float n1 = tanh_(fmaf((vc1[g] - m_) * r_, p.cw1, p.cb1));
        float h0n = fmaf(zf[0][g], n0 - hm[0][g], hm[0][g]);
        float h1n = fmaf(zf[1][g], n1 - hm[1][g], hm[1][g]);
        hm[0][g] = h0n; hm[1][g] = h1n;
        unsigned short hb0 = f2bf(h0n), hb1 = f2bf(h1n);
        h_s[crow0 + g][colr0] = hb0;
        h_s[crow0 + g][colr1] = hb1;
        if (hrow) {
          hrow[(size_t)(crow0 + g) * 256 + colr0] = hb0;
          hrow[(size_t)(crow0 + g) * 256 + colr1] = hb1;
        }
      }
    }
    __syncthreads();                                   // B4
  }
}

__device__ __forceinline__ void gru_store(float* __restrict__ hstate, int bt,
                                          float (&hm)[2][4]) {
  const int lane = threadIdx.x & 63, wv = threadIdx.x >> 6;
  const int crow0 = (lane >> 4) * 4;
  const int colr0 = 32 * wv + (lane & 15), colr1 = colr0 + 16;
  const int b0 = bt * 16;
#pragma unroll
  for (int g = 0; g < 4; ++g) {
    hstate[(size_t)(b0 + crow0 + g) * 256 + colr0] = hm[0][g];
    hstate[(size_t)(b0 + crow0 + g) * 256 + colr1] = hm[1][g];
  }
}

// ------------------------- kernel arg bundle ---------------------------------
struct PArgs {
  const float* x;
  const unsigned short *g0h, *c0h, *g1h, *c1h, *wx0, *wx1;
  const float *b768_0, *b768_1;
  const float *gnw0, *gnb0, *cnw0, *cnb0, *gnw1, *gnb1, *cnw1, *cnb1;
  float *hst1;
  unsigned short *P0r, *P1r, *h0r;
  int* flags;
  int TC, NC, R;
};

// ------------------------- persistent pipeline kernel ------------------------
__launch_bounds__(512, 2)
__global__ void pipeline(PArgs a) {
  __shared__ __align__(16) unsigned char smem[149504];
  const int bid = blockIdx.x;
  const int TC = a.TC, NC = a.NC, R = a.R;
  int* fP0 = a.flags;
  int* fL0 = a.flags + NC;
  int* fP1 = a.flags + 2 * NC;
  int* fL1 = a.flags + 3 * NC;
  const size_t chP = (size_t)TC * 393216, chH = (size_t)TC * 131072;

  if (bid < 64) {                              // ---- gru roles ----
    const bool isB = bid < 32;
    const int bt = isB ? bid : (bid - 32);
    bf16x8 wgr0[8], wgr1[8], wgr2[8], wgr3[8];
    GP p; float hm[2][4];
    gru_init(smem,
             isB ? a.g0h : a.g1h, isB ? a.c0h : a.c1h,
             isB ? a.gnw0 : a.gnw1, isB ? a.gnb0 : a.gnb1,
             isB ? a.cnw0 : a.cnw1, isB ? a.cnb0 : a.cnb1,
             wgr0, wgr1, wgr2, wgr3, p, hm);
    for (int k = 0; k < NC; ++k) {
      int slot = k & (R - 1);
      if (isB) {
        if (k >= R) waitflag(&fP1[k - R], 64);  // C done reading h0 slot
        waitflag(&fP0[k], 64);                  // P0 chunk ready
        gru_chunk(smem, bt, wgr0, wgr1, wgr2, wgr3, p, hm,
                  a.P0r + chP * slot, a.h0r + chH * slot, TC);
        postflag(&fL0[k]);
      } else {
        waitflag(&fP1[k], 64);                  // P1 chunk ready
        gru_chunk(smem, bt, wgr0, wgr1, wgr2, wgr3, p, hm,
                  a.P1r + chP * slot, (unsigned short*)nullptr, TC);
        postflag(&fL1[k]);
      }
    }
    if (!isB) gru_store(a.hst1, bt, hm);
  } else if (bid < 128) {                      // ---- A: P0 producer ----
    int team = (bid - 64) * 2 + (threadIdx.x >> 8);
    int t256 = threadIdx.x & 255;
    unsigned short* A_s = (unsigned short*)(smem + (threadIdx.x >> 8) * 32768);
    unsigned short* B_s = A_s + 8192;
    int ntile = 24 * TC;
    for (int k = 0; k < NC; ++k) {
      int slot = k & (R - 1);
      if (k >= R) waitflag(&fL0[k - R], 32);    // L0 done reading P0 slot
      unsigned short* P0 = a.P0r + chP * slot;
      for (int i = team; i < ntile; i += 128) {
        int mi = i % (4 * TC), ni = i / (4 * TC);
        precomp_tile(a.x, a.wx0, a.b768_0, P0, TC, k * TC, 64, 1,
                     mi, ni * 128, A_s, B_s, t256);
      }
      postflag(&fP0[k]);
    }
  } else {                                     // ---- C: P1 producer ----
    int team = (bid - 128) * 2 + (threadIdx.x >> 8);
    int t256 = threadIdx.x & 255;
    unsigned short* A_s = (unsigned short*)(smem + (threadIdx.x >> 8) * 32768);
    unsigned short* B_s = A_s + 8192;
    int ntile = 24 * TC;
    for (int k = 0; k < NC; ++k) {
      int slot = k & (R - 1);
      waitflag(&fL0[k], 32);                    // h0 chunk ready
      if (k >= R) waitflag(&fL1[k - R], 32);    // L1 done reading P1 slot
      const unsigned short* h0 = a.h0r + chH * slot;
      unsigned short* P1 = a.P1r + chP * slot;
      for (int i = team; i < ntile; i += 128) {
        int mi = i % (4 * TC), ni = i / (4 * TC);
        precomp_tile(h0, a.wx1, a.b768_1, P1, TC, 0, 256, 0,
                     mi, ni * 128, A_s, B_s, t256);
      }
      postflag(&fP1[k]);
    }
  }
}

// ------------------------------- FC head -------------------------------------
__launch_bounds__(256)
__global__ void head_k(const float* __restrict__ h1, const float* __restrict__ fcW,
                       const float* __restrict__ fcb, float* __restrict__ out) {
  __shared__ float hs[16][256];
  const int tid = threadIdx.x, b0 = blockIdx.x * 16;
  for (int i = tid; i < 16 * 64; i += 256) {
    int r = i >> 6, c4 = (i & 63) * 4;
    *reinterpret_cast<float4*>(&hs[r][c4]) =
        *reinterpret_cast<const float4*>(&h1[(size_t)(b0 + r) * 256 + c4]);
  }
  __syncthreads();
  int r = tid >> 4, o = (tid & 15) * 4;
  float a0 = fcb[o], a1 = fcb[o + 1], a2 = fcb[o + 2], a3 = fcb[o + 3];
  for (int k = 0; k < 256; ++k) {
    float h = hs[r][k];
    a0 = fmaf(h, fcW[(size_t)(o + 0) * 256 + k], a0);
    a1 = fmaf(h, fcW[(size_t)(o + 1) * 256 + k], a1);
    a2 = fmaf(h, fcW[(size_t)(o + 2) * 256 + k], a2);
    a3 = fmaf(h, fcW[(size_t)(o + 3) * 256 + k], a3);
  }
  float4 ov = {a0, a1, a2, a3};
  *reinterpret_cast<float4*>(&out[(size_t)(b0 + r) * 64 + o]) = ov;
}

// --------------------------------- host --------------------------------------
extern "C" void kernel_launch(void* const* d_in, const int* in_sizes, int n_in,
                              void* d_out, int out_size, void* d_ws, size_t ws_size,
                              hipStream_t stream) {
  (void)in_sizes; (void)n_in; (void)out_size;
  const float* x    = (const float*)d_in[0];
  const float* Wg0  = (const float*)d_in[1];
  const float* bg0  = (const float*)d_in[2];
  const float* gnw0 = (const float*)d_in[3];
  const float* gnb0 = (const float*)d_in[4];
  const float* Wc0  = (const float*)d_in[5];
  const float* bc0  = (const float*)d_in[6];
  const float* cnw0 = (const float*)d_in[7];
  const float* cnb0 = (const float*)d_in[8];
  const float* Wg1  = (const float*)d_in[9];
  const float* bg1  = (const float*)d_in[10];
  const float* gnw1 = (const float*)d_in[11];
  const float* gnb1 = (const float*)d_in[12];
  const float* Wc1  = (const float*)d_in[13];
  const float* bc1  = (const float*)d_in[14];
  const float* cnw1 = (const float*)d_in[15];
  const float* cnb1 = (const float*)d_in[16];
  const float* fcW  = (const float*)d_in[17];
  const float* fcb  = (const float*)d_in[18];

  int*   flags = (int*)d_ws;                          // 512 ints
  float* hst1  = (float*)(flags + 512);               // 512*256 f32
  float* b768_0 = hst1 + 131072;
  float* b768_1 = b768_0 + 768;
  unsigned short* g0h = (unsigned short*)(b768_1 + 768);
  unsigned short* c0h = g0h + 131072;
  unsigned short* g1h = c0h + 65536;
  unsigned short* c1h = g1h + 131072;
  unsigned short* wx0 = c1h + 65536;
  unsigned short* wx1 = wx0 + 49152;
  unsigned short* dynbase = wx1 + 196608;

  const size_t fixed_bytes = (size_t)((char*)dynbase - (char*)d_ws);
  int TC = 16, R = 4;
  for (;;) {
    size_t need = fixed_bytes +
        2ull * R * TC * (2ull * 393216 + 131072);      // P0,P1 rings + h0 ring (bytes)
    if (need <= ws_size) break;
    if (R > 2) { R >>= 1; continue; }
    if (TC > 4) { TC >>= 1; continue; }
    break;
  }
  const int NC = T_ / TC;

  unsigned short* P0r = dynbase;
  unsigned short* P1r = P0r + (size_t)R * TC * 393216;
  unsigned short* h0r = P1r + (size_t)R * TC * 393216;

  zero_flags<<<1, 512, 0, stream>>>(flags);
  prep_frag<<<512, 256, 0, stream>>>(Wg0, g0h, 512, 320, 64);
  prep_frag<<<256, 256, 0, stream>>>(Wc0, c0h, 256, 320, 64);
  prep_frag<<<512, 256, 0, stream>>>(Wg1, g1h, 512, 512, 256);
  prep_frag<<<256, 256, 0, stream>>>(Wc1, c1h, 256, 512, 256);
  prep_wx<<<192, 256, 0, stream>>>(Wg0, Wc0, wx0, 64, 320, 320);
  prep_wx<<<768, 256, 0, stream>>>(Wg1, Wc1, wx1, 256, 512, 512);
  bias_cat<<<3, 256, 0, stream>>>(bg0, bc0, b768_0);
  bias_cat<<<3, 256, 0, stream>>>(bg1, bc1, b768_1);

  PArgs pa;
  pa.x = x;
  pa.g0h = g0h; pa.c0h = c0h; pa.g1h = g1h; pa.c1h = c1h;
  pa.wx0 = wx0; pa.wx1 = wx1;
  pa.b768_0 = b768_0; pa.b768_1 = b768_1;
  pa.gnw0 = gnw0; pa.gnb0 = gnb0; pa.cnw0 = cnw0; pa.cnb0 = cnb0;
  pa.gnw1 = gnw1; pa.gnb1 = gnb1; pa.cnw1 = cnw1; pa.cnb1 = cnb1;
  pa.hst1 = hst1;
  pa.P0r = P0r; pa.P1r = P1r; pa.h0r = h0r;
  pa.flags = flags;
  pa.TC = TC; pa.NC = NC; pa.R = R;

  pipeline<<<192, 512, 0, stream>>>(pa);

  head_k<<<32, 256, 0, stream>>>(hst1, fcW, fcb, (float*)d_out);
}

// Round 14
// 8112.457 us; speedup vs baseline: 1.9188x; 1.9188x over previous
//
#include <hip/hip_runtime.h>

// ---------------------------------------------------------------------------
// MultiLayerNormGRU on MI355X (gfx950) — round 14.
// R7 mega pipeline; recurrent blocks now process TWO batch groups (32 rows)
// with a 6-phase / 5-barrier software-pipelined schedule so every barrier /
// LN-latency window is filled with the other group's MFMA or VALU work.
// Weights shared by both groups: gates in AGPR (128, pinned), cand in LDS.
// LDS: wc 128K | h_sX 8448 | h_sY 8448 | rh(shared) 8448 | stats 2x1K = 158.5K
// Roles per 256-block dispatch (k): 0-15 L0(k) | 16-31 L1(k-2) |
// 32-143 precomp P0(k+1) | 144-255 precomp P1(k-1). Ping-pong buffers as R7.
// ---------------------------------------------------------------------------

#define B_   512
#define T_   512
#define DIN  64
#define H_   256
#define OUT_ 64
#define EPS_ 1e-5f

typedef __attribute__((ext_vector_type(8))) short bf16x8;
typedef __attribute__((ext_vector_type(4))) float f32x4;

__device__ __forceinline__ unsigned short f2bf(float f) {
  unsigned int u = __float_as_uint(f);
  u += 0x7fffu + ((u >> 16) & 1u);
  return (unsigned short)(u >> 16);
}
__device__ __forceinline__ float bfh(unsigned short u) {
  return __uint_as_float(((unsigned int)u) << 16);
}
__device__ __forceinline__ float sigm_(float x) {
  return __builtin_amdgcn_rcpf(1.f + __expf(-x));
}
__device__ __forceinline__ float tanh_(float x) {
  return 1.f - 2.f * __builtin_amdgcn_rcpf(__expf(2.f * x) + 1.f);
}
template<int C>
__device__ __forceinline__ float dpp_add(float v) {
  int r = __builtin_amdgcn_update_dpp(0, __float_as_int(v), C, 0xF, 0xF, false);
  return v + __int_as_float(r);
}
__device__ __forceinline__ float red16(float v) {
  v = dpp_add<0x121>(v);
  v = dpp_add<0x122>(v);
  v = dpp_add<0x124>(v);
  v = dpp_add<0x128>(v);
  return v;
}

#define PIN8A(a) asm volatile("" : "+a"(a[0]), "+a"(a[1]), "+a"(a[2]), "+a"(a[3]), \
                                   "+a"(a[4]), "+a"(a[5]), "+a"(a[6]), "+a"(a[7]))

// ------------------------- prep kernels --------------------------------------
__global__ void prep_frag(const float* __restrict__ w, unsigned short* __restrict__ dst,
                          int N, int Ksrc, int koff) {
  int gid = blockIdx.x * 256 + threadIdx.x;
  if (gid >= N * 256) return;
  int n = gid >> 8, k = gid & 255;
  int idx = (((n >> 4) * 8 + (k >> 5)) * 64 + ((n & 15) + 16 * ((k >> 3) & 3))) * 8 + (k & 7);
  dst[idx] = f2bf(w[(size_t)n * Ksrc + koff + k]);
}

__global__ void prep_wx(const float* __restrict__ wg, const float* __restrict__ wc,
                        unsigned short* __restrict__ dst, int KX, int Kg, int Kc) {
  int gid = blockIdx.x * 256 + threadIdx.x;
  if (gid >= 768 * KX) return;
  int n = gid / KX, k = gid - n * KX;
  float v = (n < 512) ? wg[(size_t)n * Kg + k] : wc[(size_t)(n - 512) * Kc + k];
  dst[gid] = f2bf(v);
}

__global__ void bias_cat(const float* __restrict__ bg, const float* __restrict__ bc,
                         float* __restrict__ dst) {
  int i = blockIdx.x * 256 + threadIdx.x;
  if (i < 768) dst[i] = (i < 512) ? bg[i] : bc[i - 512];
}

// ------------------------- precomp tile (256-thread team) --------------------
__device__ __forceinline__ void precomp_tile(
    const void* __restrict__ Asrc, const unsigned short* __restrict__ wx,
    const float* __restrict__ bias, unsigned short* __restrict__ Pc,
    int TC, int t0, int KX, int AFP32,
    int mi, int nb, unsigned short* A_s, unsigned short* B_s, int t256)
{
  const int lane = t256 & 63, wv = t256 >> 6;
  const int m0 = mi * 128;
  const int bt = m0 / (TC * 16);
  const int tt0 = (m0 - bt * TC * 16) >> 4;
  const int mq = wv >> 1, nq = wv & 1;
  const int crow0 = (lane >> 4) * 4;

  f32x4 acc[4][4];
#pragma unroll
  for (int i = 0; i < 4; ++i)
#pragma unroll
    for (int j = 0; j < 4; ++j) acc[i][j] = (f32x4){0, 0, 0, 0};

  for (int kb = 0; kb < (KX >> 6); ++kb) {
    __syncthreads();
#pragma unroll
    for (int it = 0; it < 4; ++it) {
      int s = t256 + it * 256;
      int rg = s >> 3, k8 = s & 7;
      int mt = rg >> 4, r15 = rg & 15;
      int dl = r15 + 16 * (k8 & 3), kc = k8 >> 2;
      if (AFP32) {
        const float* xp = (const float*)Asrc +
            (((size_t)(bt * 16 + r15)) * T_ + (t0 + tt0 + mt)) * DIN + kb * 64 + k8 * 8;
        float4 u0 = *(const float4*)xp, u1 = *(const float4*)(xp + 4);
        unsigned short tmp[8];
        tmp[0] = f2bf(u0.x); tmp[1] = f2bf(u0.y); tmp[2] = f2bf(u0.z); tmp[3] = f2bf(u0.w);
        tmp[4] = f2bf(u1.x); tmp[5] = f2bf(u1.y); tmp[6] = f2bf(u1.z); tmp[7] = f2bf(u1.w);
        *reinterpret_cast<bf16x8*>(&A_s[((mt * 2 + kc) * 64 + dl) * 8]) =
            *reinterpret_cast<bf16x8*>(tmp);
      } else {
        const unsigned short* ap = (const unsigned short*)Asrc +
            ((size_t)(m0 + rg)) * KX + kb * 64 + k8 * 8;
        *reinterpret_cast<bf16x8*>(&A_s[((mt * 2 + kc) * 64 + dl) * 8]) =
            *reinterpret_cast<const bf16x8*>(ap);
      }
      const unsigned short* bp = wx + ((size_t)(nb + rg)) * KX + kb * 64 + k8 * 8;
      *reinterpret_cast<bf16x8*>(&B_s[((mt * 2 + kc) * 64 + dl) * 8]) =
          *reinterpret_cast<const bf16x8*>(bp);
    }
    __syncthreads();
#pragma unroll
    for (int kc = 0; kc < 2; ++kc) {
      bf16x8 av[4], bv[4];
#pragma unroll
      for (int i = 0; i < 4; ++i) {
        av[i] = *reinterpret_cast<const bf16x8*>(&A_s[(((mq * 4 + i) * 2 + kc) * 64 + lane) * 8]);
        bv[i] = *reinterpret_cast<const bf16x8*>(&B_s[(((nq * 4 + i) * 2 + kc) * 64 + lane) * 8]);
      }
#pragma unroll
      for (int i = 0; i < 4; ++i)
#pragma unroll
        for (int j = 0; j < 4; ++j)
          acc[i][j] = __builtin_amdgcn_mfma_f32_16x16x32_bf16(av[i], bv[j], acc[i][j], 0, 0, 0);
    }
  }
  float bb[4];
#pragma unroll
  for (int j = 0; j < 4; ++j) bb[j] = bias[nb + nq * 64 + j * 16 + (lane & 15)];
#pragma unroll
  for (int i = 0; i < 4; ++i) {
    int tt = tt0 + mq * 4 + i;
#pragma unroll
    for (int j = 0; j < 4; ++j) {
      int n = nb + nq * 64 + j * 16 + (lane & 15);
      ushort4 o;
      o.x = f2bf(acc[i][j][0] + bb[j]); o.y = f2bf(acc[i][j][1] + bb[j]);
      o.z = f2bf(acc[i][j][2] + bb[j]); o.w = f2bf(acc[i][j][3] + bb[j]);
      *reinterpret_cast<ushort4*>(&Pc[((size_t)(bt * TC + tt) * 768 + n) * 16 + crow0]) = o;
    }
  }
}

__launch_bounds__(256)
__global__ void precomp_std(const void* __restrict__ Asrc,
                            const unsigned short* __restrict__ wx,
                            const float* __restrict__ bias,
                            unsigned short* __restrict__ Pc,
                            int TC, int t0, int KX, int AFP32) {
  __shared__ __align__(16) unsigned short A_s[8192];
  __shared__ __align__(16) unsigned short B_s[8192];
  precomp_tile(Asrc, wx, bias, Pc, TC, t0, KX, AFP32,
               blockIdx.x, blockIdx.y * 128, A_s, B_s, threadIdx.x);
}

// ------------------------- two-group recurrent body --------------------------
// LDS: wc 0..131071 | h_sX @131072 | h_sY @139520 | rh @147968 |
//      sumX @156416 sqX @156928 sumY @157440 sqY @157952  (each [8][16] f32)
__device__ __forceinline__ void gru_body2(
    unsigned char* smem, int blk,
    const unsigned short* __restrict__ gfrag,
    const unsigned short* __restrict__ cfrag,
    const unsigned short* __restrict__ Pc,
    const float* __restrict__ gnw, const float* __restrict__ gnb,
    const float* __restrict__ cnw, const float* __restrict__ cnb,
    float* __restrict__ hstate, unsigned short* __restrict__ h0out,
    int TC, int first)
{
  unsigned short* wc_s = (unsigned short*)smem;
  unsigned short (*h_sX)[264] = (unsigned short(*)[264])(smem + 131072);
  unsigned short (*h_sY)[264] = (unsigned short(*)[264])(smem + 139520);
  unsigned short (*rh_s)[264] = (unsigned short(*)[264])(smem + 147968);
  float* sumX = (float*)(smem + 156416);
  float* sqX  = (float*)(smem + 156928);
  float* sumY = (float*)(smem + 157440);
  float* sqY  = (float*)(smem + 157952);

  const int tid = threadIdx.x, lane = tid & 63, wv = tid >> 6;
  const int bt0 = 2 * blk, bt1 = 2 * blk + 1;
  const int b0X = bt0 * 16, b0Y = bt1 * 16;
  const int arow = lane & 15, koff = (lane >> 4) * 8, crow0 = (lane >> 4) * 4;
  const int colr0 = 32 * wv + (lane & 15), colr1 = colr0 + 16;
  const int nt0 = 2 * wv, nt1 = 2 * wv + 1, nt2 = 16 + 2 * wv, nt3 = 17 + 2 * wv;

  for (int i = tid; i < 8192; i += 512)
    *reinterpret_cast<bf16x8*>(&wc_s[i * 8]) = *reinterpret_cast<const bf16x8*>(&cfrag[i * 8]);

  bf16x8 wgr0[8], wgr1[8], wgr2[8], wgr3[8];
#pragma unroll
  for (int kc = 0; kc < 8; ++kc) {
    wgr0[kc] = *reinterpret_cast<const bf16x8*>(&gfrag[((nt0 * 8 + kc) * 64 + lane) * 8]);
    wgr1[kc] = *reinterpret_cast<const bf16x8*>(&gfrag[((nt1 * 8 + kc) * 64 + lane) * 8]);
    wgr2[kc] = *reinterpret_cast<const bf16x8*>(&gfrag[((nt2 * 8 + kc) * 64 + lane) * 8]);
    wgr3[kc] = *reinterpret_cast<const bf16x8*>(&gfrag[((nt3 * 8 + kc) * 64 + lane) * 8]);
  }

  const float gw_r0 = gnw[colr0], gb_r0 = gnb[colr0];
  const float gw_r1 = gnw[colr1], gb_r1 = gnb[colr1];
  const float gw_z0 = gnw[256 + colr0], gb_z0 = gnb[256 + colr0];
  const float gw_z1 = gnw[256 + colr1], gb_z1 = gnb[256 + colr1];
  const float cw0 = cnw[colr0], cb0 = cnb[colr0];
  const float cw1 = cnw[colr1], cb1 = cnb[colr1];

  float hmX[2][4], hmY[2][4];
  if (first) {
#pragma unroll
    for (int g = 0; g < 4; ++g) {
      hmX[0][g] = 0.f; hmX[1][g] = 0.f; hmY[0][g] = 0.f; hmY[1][g] = 0.f;
    }
    for (int i = tid; i < 16 * 264; i += 512) {
      (&h_sX[0][0])[i] = 0; (&h_sY[0][0])[i] = 0;
    }
  } else {
#pragma unroll
    for (int g = 0; g < 4; ++g) {
      hmX[0][g] = hstate[(size_t)(b0X + crow0 + g) * 256 + colr0];
      hmX[1][g] = hstate[(size_t)(b0X + crow0 + g) * 256 + colr1];
      hmY[0][g] = hstate[(size_t)(b0Y + crow0 + g) * 256 + colr0];
      hmY[1][g] = hstate[(size_t)(b0Y + crow0 + g) * 256 + colr1];
    }
    int r = tid >> 5, c8 = (tid & 31) * 8;
    {
      float4 v0 = *reinterpret_cast<const float4*>(&hstate[(size_t)(b0X + r) * 256 + c8]);
      float4 v1 = *reinterpret_cast<const float4*>(&hstate[(size_t)(b0X + r) * 256 + c8 + 4]);
      ushort4 o0, o1;
      o0.x = f2bf(v0.x); o0.y = f2bf(v0.y); o0.z = f2bf(v0.z); o0.w = f2bf(v0.w);
      o1.x = f2bf(v1.x); o1.y = f2bf(v1.y); o1.z = f2bf(v1.z); o1.w = f2bf(v1.w);
      *reinterpret_cast<ushort4*>(&h_sX[r][c8]) = o0;
      *reinterpret_cast<ushort4*>(&h_sX[r][c8 + 4]) = o1;
    }
    {
      float4 v0 = *reinterpret_cast<const float4*>(&hstate[(size_t)(b0Y + r) * 256 + c8]);
      float4 v1 = *reinterpret_cast<const float4*>(&hstate[(size_t)(b0Y + r) * 256 + c8 + 4]);
      ushort4 o0, o1;
      o0.x = f2bf(v0.x); o0.y = f2bf(v0.y); o0.z = f2bf(v0.z); o0.w = f2bf(v0.w);
      o1.x = f2bf(v1.x); o1.y = f2bf(v1.y); o1.z = f2bf(v1.z); o1.w = f2bf(v1.w);
      *reinterpret_cast<ushort4*>(&h_sY[r][c8]) = o0;
      *reinterpret_cast<ushort4*>(&h_sY[r][c8 + 4]) = o1;
    }
  }
  __syncthreads();

  const unsigned short* PrX = Pc + ((size_t)bt0 * TC * 768 + colr0) * 16;
  const unsigned short* PrY = Pc + ((size_t)bt1 * TC * 768 + colr0) * 16;

  for (int tt = 0; tt < TC; ++tt) {
    PIN8A(wgr0); PIN8A(wgr1); PIN8A(wgr2); PIN8A(wgr3);

    // ========== Phase 1: X gates MFMA + X gate stats ==========
    ushort4 xr0 = *reinterpret_cast<const ushort4*>(PrX + crow0);
    ushort4 xr1 = *reinterpret_cast<const ushort4*>(PrX + 256 + crow0);
    ushort4 xz0 = *reinterpret_cast<const ushort4*>(PrX + 4096 + crow0);
    ushort4 xz1 = *reinterpret_cast<const ushort4*>(PrX + 4352 + crow0);
    f32x4 a0 = {0,0,0,0}, a1 = {0,0,0,0}, a2 = {0,0,0,0}, a3 = {0,0,0,0};
#pragma unroll
    for (int kc = 0; kc < 8; ++kc) {
      bf16x8 av = *reinterpret_cast<const bf16x8*>(&h_sX[arow][kc * 32 + koff]);
      a0 = __builtin_amdgcn_mfma_f32_16x16x32_bf16(av, wgr0[kc], a0, 0, 0, 0);
      a1 = __builtin_amdgcn_mfma_f32_16x16x32_bf16(av, wgr1[kc], a1, 0, 0, 0);
      a2 = __builtin_amdgcn_mfma_f32_16x16x32_bf16(av, wgr2[kc], a2, 0, 0, 0);
      a3 = __builtin_amdgcn_mfma_f32_16x16x32_bf16(av, wgr3[kc], a3, 0, 0, 0);
    }
    float vrX0[4], vrX1[4], vzX0[4], vzX1[4];
#pragma unroll
    for (int g = 0; g < 4; ++g) {
      vrX0[g] = a0[g] + bfh(((const unsigned short*)&xr0)[g]);
      vrX1[g] = a1[g] + bfh(((const unsigned short*)&xr1)[g]);
      vzX0[g] = a2[g] + bfh(((const unsigned short*)&xz0)[g]);
      vzX1[g] = a3[g] + bfh(((const unsigned short*)&xz1)[g]);
      float s = red16(vrX0[g] + vrX1[g] + vzX0[g] + vzX1[g]);
      float q = red16(vrX0[g]*vrX0[g] + vrX1[g]*vrX1[g] + vzX0[g]*vzX0[g] + vzX1[g]*vzX1[g]);
      if ((lane & 15) == 0) { sumX[wv * 16 + crow0 + g] = s; sqX[wv * 16 + crow0 + g] = q; }
    }
    __syncthreads();                                   // B1

    // ========== Phase 2: Y gates MFMA + Y stats ; X gate-LN -> rh ==========
    ushort4 yr0 = *reinterpret_cast<const ushort4*>(PrY + crow0);
    ushort4 yr1 = *reinterpret_cast<const ushort4*>(PrY + 256 + crow0);
    ushort4 yz0 = *reinterpret_cast<const ushort4*>(PrY + 4096 + crow0);
    ushort4 yz1 = *reinterpret_cast<const ushort4*>(PrY + 4352 + crow0);
    f32x4 b0 = {0,0,0,0}, b1 = {0,0,0,0}, b2 = {0,0,0,0}, b3 = {0,0,0,0};
#pragma unroll
    for (int kc = 0; kc < 8; ++kc) {
      bf16x8 av = *reinterpret_cast<const bf16x8*>(&h_sY[arow][kc * 32 + koff]);
      b0 = __builtin_amdgcn_mfma_f32_16x16x32_bf16(av, wgr0[kc], b0, 0, 0, 0);
      b1 = __builtin_amdgcn_mfma_f32_16x16x32_bf16(av, wgr1[kc], b1, 0, 0, 0);
      b2 = __builtin_amdgcn_mfma_f32_16x16x32_bf16(av, wgr2[kc], b2, 0, 0, 0);
      b3 = __builtin_amdgcn_mfma_f32_16x16x32_bf16(av, wgr3[kc], b3, 0, 0, 0);
    }
    float vrY0[4], vrY1[4], vzY0[4], vzY1[4];
#pragma unroll
    for (int g = 0; g < 4; ++g) {
      vrY0[g] = b0[g] + bfh(((const unsigned short*)&yr0)[g]);
      vrY1[g] = b1[g] + bfh(((const unsigned short*)&yr1)[g]);
      vzY0[g] = b2[g] + bfh(((const unsigned short*)&yz0)[g]);
      vzY1[g] = b3[g] + bfh(((const unsigned short*)&yz1)[g]);
      float s = red16(vrY0[g] + vrY1[g] + vzY0[g] + vzY1[g]);
      float q = red16(vrY0[g]*vrY0[g] + vrY1[g]*vrY1[g] + vzY0[g]*vzY0[g] + vzY1[g]*vzY1[g]);
      if ((lane & 15) == 0) { sumY[wv * 16 + crow0 + g] = s; sqY[wv * 16 + crow0 + g] = q; }
    }
    float zfX[2][4];
    {
      int sg = lane >> 4, rr = lane & 15;
      float S = sumX[2 * sg * 16 + rr] + sumX[(2 * sg + 1) * 16 + rr];
      float Q = sqX[2 * sg * 16 + rr] + sqX[(2 * sg + 1) * 16 + rr];
      S += __shfl_xor(S, 16, 64); Q += __shfl_xor(Q, 16, 64);
      S += __shfl_xor(S, 32, 64); Q += __shfl_xor(Q, 32, 64);
      float mn = S * (1.f / 512.f);
      float rs = __builtin_amdgcn_rsqf(Q * (1.f / 512.f) - mn * mn + EPS_);
#pragma unroll
      for (int g = 0; g < 4; ++g) {
        float m_ = __shfl(mn, crow0 + g, 64);
        float r_ = __shfl(rs, crow0 + g, 64);
        float rv0 = sigm_(fmaf((vrX0[g] - m_) * r_, gw_r0, gb_r0));
        float rv1 = sigm_(fmaf((vrX1[g] - m_) * r_, gw_r1, gb_r1));
        zfX[0][g] = sigm_(fmaf((vzX0[g] - m_) * r_, gw_z0, gb_z0));
        zfX[1][g] = sigm_(fmaf((vzX1[g] - m_) * r_, gw_z1, gb_z1));
        rh_s[crow0 + g][colr0] = f2bf(rv0 * hmX[0][g]);
        rh_s[crow0 + g][colr1] = f2bf(rv1 * hmX[1][g]);
      }
    }
    __syncthreads();                                   // B2

    // ========== Phase 3: X cand MFMA + stats ; Y gate-LN (rh write deferred) ==========
    ushort4 xn0 = *reinterpret_cast<const ushort4*>(PrX + 8192 + crow0);
    ushort4 xn1 = *reinterpret_cast<const ushort4*>(PrX + 8448 + crow0);
    f32x4 c0 = {0,0,0,0}, c1 = {0,0,0,0};
#pragma unroll
    for (int kc = 0; kc < 8; ++kc) {
      bf16x8 av = *reinterpret_cast<const bf16x8*>(&rh_s[arow][kc * 32 + koff]);
      bf16x8 w0 = *reinterpret_cast<const bf16x8*>(&wc_s[((nt0 * 8 + kc) * 64 + lane) * 8]);
      bf16x8 w1 = *reinterpret_cast<const bf16x8*>(&wc_s[((nt1 * 8 + kc) * 64 + lane) * 8]);
      c0 = __builtin_amdgcn_mfma_f32_16x16x32_bf16(av, w0, c0, 0, 0, 0);
      c1 = __builtin_amdgcn_mfma_f32_16x16x32_bf16(av, w1, c1, 0, 0, 0);
    }
    float vcX0[4], vcX1[4];
#pragma unroll
    for (int g = 0; g < 4; ++g) {
      vcX0[g] = c0[g] + bfh(((const unsigned short*)&xn0)[g]);
      vcX1[g] = c1[g] + bfh(((const unsigned short*)&xn1)[g]);
      float s = red16(vcX0[g] + vcX1[g]);
      float q = red16(vcX0[g]*vcX0[g] + vcX1[g]*vcX1[g]);
      if ((lane & 15) == 0) { sumX[wv * 16 + crow0 + g] = s; sqX[wv * 16 + crow0 + g] = q; }
    }
    float zfY[2][4], rhv0[4], rhv1[4];
    {
      int sg = lane >> 4, rr = lane & 15;
      float S = sumY[2 * sg * 16 + rr] + sumY[(2 * sg + 1) * 16 + rr];
      float Q = sqY[2 * sg * 16 + rr] + sqY[(2 * sg + 1) * 16 + rr];
      S += __shfl_xor(S, 16, 64); Q += __shfl_xor(Q, 16, 64);
      S += __shfl_xor(S, 32, 64); Q += __shfl_xor(Q, 32, 64);
      float mn = S * (1.f / 512.f);
      float rs = __builtin_amdgcn_rsqf(Q * (1.f / 512.f) - mn * mn + EPS_);
#pragma unroll
      for (int g = 0; g < 4; ++g) {
        float m_ = __shfl(mn, crow0 + g, 64);
        float r_ = __shfl(rs, crow0 + g, 64);
        float rv0 = sigm_(fmaf((vrY0[g] - m_) * r_, gw_r0, gb_r0));
        float rv1 = sigm_(fmaf((vrY1[g] - m_) * r_, gw_r1, gb_r1));
        zfY[0][g] = sigm_(fmaf((vzY0[g] - m_) * r_, gw_z0, gb_z0));
        zfY[1][g] = sigm_(fmaf((vzY1[g] - m_) * r_, gw_z1, gb_z1));
        rhv0[g] = rv0 * hmY[0][g];
        rhv1[g] = rv1 * hmY[1][g];
      }
    }
    __syncthreads();                                   // B3

    // ========== Phase 4: Y rh write ; X cand-LN + update ==========
#pragma unroll
    for (int g = 0; g < 4; ++g) {
      rh_s[crow0 + g][colr0] = f2bf(rhv0[g]);
      rh_s[crow0 + g][colr1] = f2bf(rhv1[g]);
    }
    {
      int sg = lane >> 4, rr = lane & 15;
      float S = sumX[2 * sg * 16 + rr] + sumX[(2 * sg + 1) * 16 + rr];
      float Q = sqX[2 * sg * 16 + rr] + sqX[(2 * sg + 1) * 16 + rr];
      S += __shfl_xor(S, 16, 64); Q += __shfl_xor(Q, 16, 64);
      S += __shfl_xor(S, 32, 64); Q += __shfl_xor(Q, 32, 64);
      float mn = S * (1.f / 256.f);
      float rs = __builtin_amdgcn_rsqf(Q * (1.f / 256.f) - mn * mn + EPS_);
      unsigned short* hrow = h0out ? (h0out + (size_t)(bt0 * TC + tt) * 4096)
                                   : (unsigned short*)nullptr;
#pragma unroll
      for (int g = 0; g < 4; ++g) {
        float m_ = __shfl(mn, crow0 + g, 64);
        float r_ = __shfl(rs, crow0 + g, 64);
        float n0 = tanh_(fmaf((vcX0[g] - m_) * r_, cw0, cb0));
        float n1 = tanh_(fmaf((vcX1[g] - m_) * r_, cw1, cb1));
        float h0n = fmaf(zfX[0][g], n0 - hmX[0][g], hmX[0][g]);
        float h1n = fmaf(zfX[1][g], n1 - hmX[1][g], hmX[1][g]);
        hmX[0][g] = h0n; hmX[1][g] = h1n;
        unsigned short hb0 = f2bf(h0n), hb1 = f2bf(h1n);
        h_sX[crow0 + g][colr0] = hb0;
        h_sX[crow0 + g][colr1] = hb1;
        if (hrow) {
          hrow[(size_t)(crow0 + g) * 256 + colr0] = hb0;
          hrow[(size_t)(crow0 + g) * 256 + colr1] = hb1;
        }
      }
    }
    __syncthreads();                                   // B4

    // ========== Phase 5: Y cand MFMA + stats ==========
    ushort4 yn0 = *reinterpret_cast<const ushort4*>(PrY + 8192 + crow0);
    ushort4 yn1 = *reinterpret_cast<const ushort4*>(PrY + 8448 + crow0);
    f32x4 d0 = {0,0,0,0}, d1 = {0,0,0,0};
#pragma unroll
    for (int kc = 0; kc < 8; ++kc) {
      bf16x8 av = *reinterpret_cast<const bf16x8*>(&rh_s[arow][kc * 32 + koff]);
      bf16x8 w0 = *reinterpret_cast<const bf16x8*>(&wc_s[((nt0 * 8 + kc) * 64 + lane) * 8]);
      bf16x8 w1 = *reinterpret_cast<const bf16x8*>(&wc_s[((nt1 * 8 + kc) * 64 + lane) * 8]);
      d0 = __builtin_amdgcn_mfma_f32_16x16x32_bf16(av, w0, d0, 0, 0, 0);
      d1 = __builtin_amdgcn_mfma_f32_16x16x32_bf16(av, w1, d1, 0, 0, 0);
    }
    float vcY0[4], vcY1[4];
#pragma unroll
    for (int g = 0; g < 4; ++g) {
      vcY0[g] = d0[g] + bfh(((const unsigned short*)&yn0)[g]);
      vcY1[g] = d1[g] + bfh(((const unsigned short*)&yn1)[g]);
      float s = red16(vcY0[g] + vcY1[g]);
      float q = red16(vcY0[g]*vcY0[g] + vcY1[g]*vcY1[g]);
      if ((lane & 15) == 0) { sumY[wv * 16 + crow0 + g] = s; sqY[wv * 16 + crow0 + g] = q; }
    }
    __syncthreads();                                   // B5

    // ========== Phase 6: Y cand-LN + update (no trailing barrier) ==========
    {
      int sg = lane >> 4, rr = lane & 15;
      float S = sumY[2 * sg * 16 + rr] + sumY[(2 * sg + 1) * 16 + rr];
      float Q = sqY[2 * sg * 16 + rr] + sqY[(2 * sg + 1) * 16 + rr];
      S += __shfl_xor(S, 16, 64); Q += __shfl_xor(Q, 16, 64);
      S += __shfl_xor(S, 32, 64); Q += __shfl_xor(Q, 32, 64);
      float mn = S * (1.f / 256.f);
      float rs = __builtin_amdgcn_rsqf(Q * (1.f / 256.f) - mn * mn + EPS_);
      unsigned short* hrow = h0out ? (h0out + (size_t)(bt1 * TC + tt) * 4096)
                                   : (unsigned short*)nullptr;
#pragma unroll
      for (int g = 0; g < 4; ++g) {
        float m_ = __shfl(mn, crow0 + g, 64);
        float r_ = __shfl(rs, crow0 + g, 64);
        float n0 = tanh_(fmaf((vcY0[g] - m_) * r_, cw0, cb0));
        float n1 = tanh_(fmaf((vcY1[g] - m_) * r_, cw1, cb1));
        float h0n = fmaf(zfY[0][g], n0 - hmY[0][g], hmY[0][g]);
        float h1n = fmaf(zfY[1][g], n1 - hmY[1][g], hmY[1][g]);
        hmY[0][g] = h0n; hmY[1][g] = h1n;
        unsigned short hb0 = f2bf(h0n), hb1 = f2bf(h1n);
        h_sY[crow0 + g][colr0] = hb0;
        h_sY[crow0 + g][colr1] = hb1;
        if (hrow) {
          hrow[(size_t)(crow0 + g) * 256 + colr0] = hb0;
          hrow[(size_t)(crow0 + g) * 256 + colr1] = hb1;
        }
      }
    }
    PrX += 12288; PrY += 12288;
  }
  __syncthreads();

#pragma unroll
  for (int g = 0; g < 4; ++g) {
    hstate[(size_t)(b0X + crow0 + g) * 256 + colr0] = hmX[0][g];
    hstate[(size_t)(b0X + crow0 + g) * 256 + colr1] = hmX[1][g];
    hstate[(size_t)(b0Y + crow0 + g) * 256 + colr0] = hmY[0][g];
    hstate[(size_t)(b0Y + crow0 + g) * 256 + colr1] = hmY[1][g];
  }
}

// ------------------------------- mega kernel ---------------------------------
__launch_bounds__(512, 2)
__global__ void mega(
    const float* __restrict__ x,
    const unsigned short* __restrict__ g0h, const unsigned short* __restrict__ c0h,
    const unsigned short* __restrict__ g1h, const unsigned short* __restrict__ c1h,
    const unsigned short* __restrict__ wx0, const unsigned short* __restrict__ wx1,
    const float* __restrict__ b768_0, const float* __restrict__ b768_1,
    const float* __restrict__ gnw0, const float* __restrict__ gnb0,
    const float* __restrict__ cnw0, const float* __restrict__ cnb0,
    const float* __restrict__ gnw1, const float* __restrict__ gnb1,
    const float* __restrict__ cnw1, const float* __restrict__ cnb1,
    float* __restrict__ hst0, float* __restrict__ hst1,
    unsigned short* __restrict__ P0a, unsigned short* __restrict__ P0b,
    unsigned short* __restrict__ P1a, unsigned short* __restrict__ P1b,
    unsigned short* __restrict__ h0a, unsigned short* __restrict__ h0b,
    int k, int TC, int NC)
{
  __shared__ __align__(16) unsigned char smem[158976];
  const int bid = blockIdx.x;

  if (bid < 16) {                       // ---- B: layer-0 chunk k (2 groups) ----
    if (k >= NC) return;
    unsigned short* P0 = (k & 1) ? P0b : P0a;
    unsigned short* h0 = (k & 1) ? h0b : h0a;
    gru_body2(smem, bid, g0h, c0h, P0, gnw0, gnb0, cnw0, cnb0, hst0, h0, TC, k == 0);
  } else if (bid < 32) {                // ---- D: layer-1 chunk k-2 ----
    int kD = k - 2;
    if (kD < 0 || kD >= NC) return;
    unsigned short* P1 = (kD & 1) ? P1b : P1a;
    gru_body2(smem, bid - 16, g1h, c1h, P1, gnw1, gnb1, cnw1, cnb1, hst1,
              (unsigned short*)nullptr, TC, kD == 0);
  } else if (bid < 144) {               // ---- A: precomp P0 chunk k+1 ----
    int kA = k + 1;
    if (kA >= NC) return;
    unsigned short* P0 = (kA & 1) ? P0b : P0a;
    int team = (bid - 32) * 2 + (threadIdx.x >> 8);
    int t256 = threadIdx.x & 255;
    unsigned short* A_s = (unsigned short*)(smem + (threadIdx.x >> 8) * 32768);
    unsigned short* B_s = A_s + 8192;
    int ntile = 24 * TC;
    for (int i = team; i < ntile; i += 224) {
      int mi = i % (4 * TC), ni = i / (4 * TC);
      precomp_tile(x, wx0, b768_0, P0, TC, kA * TC, 64, 1, mi, ni * 128, A_s, B_s, t256);
    }
  } else {                              // ---- C: precomp P1 chunk k-1 ----
    int kC = k - 1;
    if (kC < 0 || kC >= NC) return;
    const unsigned short* h0 = (kC & 1) ? h0b : h0a;
    unsigned short* P1 = (kC & 1) ? P1b : P1a;
    int team = (bid - 144) * 2 + (threadIdx.x >> 8);
    int t256 = threadIdx.x & 255;
    unsigned short* A_s = (unsigned short*)(smem + (threadIdx.x >> 8) * 32768);
    unsigned short* B_s = A_s + 8192;
    int ntile = 24 * TC;
    for (int i = team; i < ntile; i += 224) {
      int mi = i % (4 * TC), ni = i / (4 * TC);
      precomp_tile(h0, wx1, b768_1, P1, TC, 0, 256, 0, mi, ni * 128, A_s, B_s, t256);
    }
  }
}

// ------------------------------- FC head -------------------------------------
__launch_bounds__(256)
__global__ void head_k(const float* __restrict__ h1, const float* __restrict__ fcW,
                       const float* __restrict__ fcb, float* __restrict__ out) {
  __shared__ float hs[16][256];
  const int tid = threadIdx.x, b0 = blockIdx.x * 16;
  for (int i = tid; i < 16 * 64; i += 256) {
    int r = i >> 6, c4 = (i & 63) * 4;
    *reinterpret_cast<float4*>(&hs[r][c4]) =
        *reinterpret_cast<const float4*>(&h1[(size_t)(b0 + r) * 256 + c4]);
  }
  __syncthreads();
  int r = tid >> 4, o = (tid & 15) * 4;
  float a0 = fcb[o], a1 = fcb[o + 1], a2 = fcb[o + 2], a3 = fcb[o + 3];
  for (int k = 0; k < 256; ++k) {
    float h = hs[r][k];
    a0 = fmaf(h, fcW[(size_t)(o + 0) * 256 + k], a0);
    a1 = fmaf(h, fcW[(size_t)(o + 1) * 256 + k], a1);
    a2 = fmaf(h, fcW[(size_t)(o + 2) * 256 + k], a2);
    a3 = fmaf(h, fcW[(size_t)(o + 3) * 256 + k], a3);
  }
  float4 ov = {a0, a1, a2, a3};
  *reinterpret_cast<float4*>(&out[(size_t)(b0 + r) * 64 + o]) = ov;
}

// --------------------------------- host --------------------------------------
extern "C" void kernel_launch(void* const* d_in, const int* in_sizes, int n_in,
                              void* d_out, int out_size, void* d_ws, size_t ws_size,
                              hipStream_t stream) {
  (void)in_sizes; (void)n_in; (void)out_size;
  const float* x    = (const float*)d_in[0];
  const float* Wg0  = (const float*)d_in[1];
  const float* bg0  = (const float*)d_in[2];
  const float* gnw0 = (const float*)d_in[3];
  const float* gnb0 = (const float*)d_in[4];
  const float* Wc0  = (const float*)d_in[5];
  const float* bc0  = (const float*)d_in[6];
  const float* cnw0 = (const float*)d_in[7];
  const float* cnb0 = (const float*)d_in[8];
  const float* Wg1  = (const float*)d_in[9];
  const float* bg1  = (const float*)d_in[10];
  const float* gnw1 = (const float*)d_in[11];
  const float* gnb1 = (const float*)d_in[12];
  const float* Wc1  = (const float*)d_in[13];
  const float* bc1  = (const float*)d_in[14];
  const float* cnw1 = (const float*)d_in[15];
  const float* cnb1 = (const float*)d_in[16];
  const float* fcW  = (const float*)d_in[17];
  const float* fcb  = (const float*)d_in[18];

  float* hst0 = (float*)d_ws;
  float* hst1 = hst0 + 131072;
  float* b768_0 = hst1 + 131072;
  float* b768_1 = b768_0 + 768;
  unsigned short* g0h = (unsigned short*)(b768_1 + 768);
  unsigned short* c0h = g0h + 131072;
  unsigned short* g1h = c0h + 65536;
  unsigned short* c1h = g1h + 131072;
  unsigned short* wx0 = c1h + 65536;
  unsigned short* wx1 = wx0 + 49152;
  unsigned short* dynbase = wx1 + 196608;

  const size_t fixed_bytes = (size_t)((char*)dynbase - (char*)d_ws);
  int TC = 32;
  while (TC > 4) {
    size_t need = fixed_bytes + (size_t)TC * 3670016;
    if (need <= ws_size) break;
    TC >>= 1;
  }
  const int NC = T_ / TC;

  unsigned short* P0a = dynbase;
  unsigned short* P0b = P0a + (size_t)TC * 393216;
  unsigned short* P1a = P0b + (size_t)TC * 393216;
  unsigned short* P1b = P1a + (size_t)TC * 393216;
  unsigned short* h0a = P1b + (size_t)TC * 393216;
  unsigned short* h0b = h0a + (size_t)TC * 131072;

  prep_frag<<<512, 256, 0, stream>>>(Wg0, g0h, 512, 320, 64);
  prep_frag<<<256, 256, 0, stream>>>(Wc0, c0h, 256, 320, 64);
  prep_frag<<<512, 256, 0, stream>>>(Wg1, g1h, 512, 512, 256);
  prep_frag<<<256, 256, 0, stream>>>(Wc1, c1h, 256, 512, 256);
  prep_wx<<<192, 256, 0, stream>>>(Wg0, Wc0, wx0, 64, 320, 320);
  prep_wx<<<768, 256, 0, stream>>>(Wg1, Wc1, wx1, 256, 512, 512);
  bias_cat<<<3, 256, 0, stream>>>(bg0, bc0, b768_0);
  bias_cat<<<3, 256, 0, stream>>>(bg1, bc1, b768_1);

  // prologue: A(0) -> P0a
  precomp_std<<<dim3(4 * TC, 6), 256, 0, stream>>>(x, wx0, b768_0, P0a, TC, 0, 64, 1);

  for (int k = 0; k < NC + 2; ++k) {
    mega<<<256, 512, 0, stream>>>(x, g0h, c0h, g1h, c1h, wx0, wx1, b768_0, b768_1,
        gnw0, gnb0, cnw0, cnb0, gnw1, gnb1, cnw1, cnb1,
        hst0, hst1, P0a, P0b, P1a, P1b, h0a, h0b, k, TC, NC);
  }

  head_k<<<32, 256, 0, stream>>>(hst1, fcW, fcb, (float*)d_out);
}

// Round 15
// 2628.058 us; speedup vs baseline: 5.9232x; 3.0869x over previous
//
#include <hip/hip_runtime.h>

// ---------------------------------------------------------------------------
// MultiLayerNormGRU on MI355X (gfx950) — round 15 = exact R7 (measured best,
// 2632 us). Mega pipeline (one dispatch per chunk; roles 0-31 L0(k),
// 32-63 L1(k-2), 64-159 precomp P0(k+1), 160-255 precomp P1(k-1); ping-pong
// buffers), recurrent body with AGPR-pinned gate weights, LDS cand weights,
// shfl-LN and 1-step P prefetch. TC=32.
// Bracketing experiments (all regressed): TC=64 (R12 2814), mnrs-LN (R10
// 2738), coop grid.sync (R11 3517), spin-flags (R13 15566), 2-group phase
// pipelining (R14 8112), full register residency (R5/R9).
// ---------------------------------------------------------------------------

#define B_   512
#define T_   512
#define DIN  64
#define H_   256
#define OUT_ 64
#define EPS_ 1e-5f

typedef __attribute__((ext_vector_type(8))) short bf16x8;
typedef __attribute__((ext_vector_type(4))) float f32x4;

__device__ __forceinline__ unsigned short f2bf(float f) {
  unsigned int u = __float_as_uint(f);
  u += 0x7fffu + ((u >> 16) & 1u);          // RNE f32 -> bf16
  return (unsigned short)(u >> 16);
}
__device__ __forceinline__ float bfh(unsigned short u) {
  return __uint_as_float(((unsigned int)u) << 16);
}
__device__ __forceinline__ float sigm_(float x) {
  return __builtin_amdgcn_rcpf(1.f + __expf(-x));
}
__device__ __forceinline__ float tanh_(float x) {
  return 1.f - 2.f * __builtin_amdgcn_rcpf(__expf(2.f * x) + 1.f);
}
template<int C>
__device__ __forceinline__ float dpp_add(float v) {
  int r = __builtin_amdgcn_update_dpp(0, __float_as_int(v), C, 0xF, 0xF, false);
  return v + __int_as_float(r);
}
__device__ __forceinline__ float red16(float v) {  // sum over 16-lane row
  v = dpp_add<0x121>(v);
  v = dpp_add<0x122>(v);
  v = dpp_add<0x124>(v);
  v = dpp_add<0x128>(v);
  return v;
}

#define PIN8A(a) asm volatile("" : "+a"(a[0]), "+a"(a[1]), "+a"(a[2]), "+a"(a[3]), \
                                   "+a"(a[4]), "+a"(a[5]), "+a"(a[6]), "+a"(a[7]))

// ------------------------- prep kernels --------------------------------------
__global__ void prep_frag(const float* __restrict__ w, unsigned short* __restrict__ dst,
                          int N, int Ksrc, int koff) {
  int gid = blockIdx.x * 256 + threadIdx.x;
  if (gid >= N * 256) return;
  int n = gid >> 8, k = gid & 255;
  int idx = (((n >> 4) * 8 + (k >> 5)) * 64 + ((n & 15) + 16 * ((k >> 3) & 3))) * 8 + (k & 7);
  dst[idx] = f2bf(w[(size_t)n * Ksrc + koff + k]);
}

__global__ void prep_wx(const float* __restrict__ wg, const float* __restrict__ wc,
                        unsigned short* __restrict__ dst, int KX, int Kg, int Kc) {
  int gid = blockIdx.x * 256 + threadIdx.x;
  if (gid >= 768 * KX) return;
  int n = gid / KX, k = gid - n * KX;
  float v = (n < 512) ? wg[(size_t)n * Kg + k] : wc[(size_t)(n - 512) * Kc + k];
  dst[gid] = f2bf(v);
}

__global__ void bias_cat(const float* __restrict__ bg, const float* __restrict__ bc,
                         float* __restrict__ dst) {
  int i = blockIdx.x * 256 + threadIdx.x;
  if (i < 768) dst[i] = (i < 512) ? bg[i] : bc[i - 512];
}

// ------------------------- precomp tile (256-thread team) --------------------
__device__ __forceinline__ void precomp_tile(
    const void* __restrict__ Asrc, const unsigned short* __restrict__ wx,
    const float* __restrict__ bias, unsigned short* __restrict__ Pc,
    int TC, int t0, int KX, int AFP32,
    int mi, int nb, unsigned short* A_s, unsigned short* B_s, int t256)
{
  const int lane = t256 & 63, wv = t256 >> 6;     // wv 0..3
  const int m0 = mi * 128;
  const int bt = m0 / (TC * 16);
  const int tt0 = (m0 - bt * TC * 16) >> 4;
  const int mq = wv >> 1, nq = wv & 1;
  const int crow0 = (lane >> 4) * 4;

  f32x4 acc[4][4];
#pragma unroll
  for (int i = 0; i < 4; ++i)
#pragma unroll
    for (int j = 0; j < 4; ++j) acc[i][j] = (f32x4){0, 0, 0, 0};

  for (int kb = 0; kb < (KX >> 6); ++kb) {
    __syncthreads();
#pragma unroll
    for (int it = 0; it < 4; ++it) {
      int s = t256 + it * 256;
      int rg = s >> 3, k8 = s & 7;
      int mt = rg >> 4, r15 = rg & 15;
      int dl = r15 + 16 * (k8 & 3), kc = k8 >> 2;
      if (AFP32) {
        const float* xp = (const float*)Asrc +
            (((size_t)(bt * 16 + r15)) * T_ + (t0 + tt0 + mt)) * DIN + kb * 64 + k8 * 8;
        float4 u0 = *(const float4*)xp, u1 = *(const float4*)(xp + 4);
        unsigned short tmp[8];
        tmp[0] = f2bf(u0.x); tmp[1] = f2bf(u0.y); tmp[2] = f2bf(u0.z); tmp[3] = f2bf(u0.w);
        tmp[4] = f2bf(u1.x); tmp[5] = f2bf(u1.y); tmp[6] = f2bf(u1.z); tmp[7] = f2bf(u1.w);
        *reinterpret_cast<bf16x8*>(&A_s[((mt * 2 + kc) * 64 + dl) * 8]) =
            *reinterpret_cast<bf16x8*>(tmp);
      } else {
        const unsigned short* ap = (const unsigned short*)Asrc +
            ((size_t)(m0 + rg)) * KX + kb * 64 + k8 * 8;
        *reinterpret_cast<bf16x8*>(&A_s[((mt * 2 + kc) * 64 + dl) * 8]) =
            *reinterpret_cast<const bf16x8*>(ap);
      }
      const unsigned short* bp = wx + ((size_t)(nb + rg)) * KX + kb * 64 + k8 * 8;
      *reinterpret_cast<bf16x8*>(&B_s[((mt * 2 + kc) * 64 + dl) * 8]) =
          *reinterpret_cast<const bf16x8*>(bp);
    }
    __syncthreads();
#pragma unroll
    for (int kc = 0; kc < 2; ++kc) {
      bf16x8 av[4], bv[4];
#pragma unroll
      for (int i = 0; i < 4; ++i) {
        av[i] = *reinterpret_cast<const bf16x8*>(&A_s[(((mq * 4 + i) * 2 + kc) * 64 + lane) * 8]);
        bv[i] = *reinterpret_cast<const bf16x8*>(&B_s[(((nq * 4 + i) * 2 + kc) * 64 + lane) * 8]);
      }
#pragma unroll
      for (int i = 0; i < 4; ++i)
#pragma unroll
        for (int j = 0; j < 4; ++j)
          acc[i][j] = __builtin_amdgcn_mfma_f32_16x16x32_bf16(av[i], bv[j], acc[i][j], 0, 0, 0);
    }
  }
  float bb[4];
#pragma unroll
  for (int j = 0; j < 4; ++j) bb[j] = bias[nb + nq * 64 + j * 16 + (lane & 15)];
#pragma unroll
  for (int i = 0; i < 4; ++i) {
    int tt = tt0 + mq * 4 + i;
#pragma unroll
    for (int j = 0; j < 4; ++j) {
      int n = nb + nq * 64 + j * 16 + (lane & 15);
      ushort4 o;
      o.x = f2bf(acc[i][j][0] + bb[j]); o.y = f2bf(acc[i][j][1] + bb[j]);
      o.z = f2bf(acc[i][j][2] + bb[j]); o.w = f2bf(acc[i][j][3] + bb[j]);
      *reinterpret_cast<ushort4*>(&Pc[((size_t)(bt * TC + tt) * 768 + n) * 16 + crow0]) = o;
    }
  }
}

// standalone wrapper for the prologue A(0)
__launch_bounds__(256)
__global__ void precomp_std(const void* __restrict__ Asrc,
                            const unsigned short* __restrict__ wx,
                            const float* __restrict__ bias,
                            unsigned short* __restrict__ Pc,
                            int TC, int t0, int KX, int AFP32) {
  __shared__ __align__(16) unsigned short A_s[8192];
  __shared__ __align__(16) unsigned short B_s[8192];
  precomp_tile(Asrc, wx, bias, Pc, TC, t0, KX, AFP32,
               blockIdx.x, blockIdx.y * 128, A_s, B_s, threadIdx.x);
}

// ------------------------- recurrent body (8 waves) --------------------------
__device__ __forceinline__ void gru_body(
    unsigned char* smem, int bt,
    const unsigned short* __restrict__ gfrag,
    const unsigned short* __restrict__ cfrag,
    const unsigned short* __restrict__ Pc,
    const float* __restrict__ gnw, const float* __restrict__ gnb,
    const float* __restrict__ cnw, const float* __restrict__ cnb,
    float* __restrict__ hstate, unsigned short* __restrict__ h0out,
    int TC, int first)
{
  unsigned short* wc_s = (unsigned short*)smem;                          // 128 KB
  unsigned short (*h_s)[264]  = (unsigned short(*)[264])(smem + 131072); // 8448 B
  unsigned short (*rh_s)[264] = (unsigned short(*)[264])(smem + 139520); // 8448 B
  float (*sumP)[20] = (float(*)[20])(smem + 147968);                     // 640 B
  float (*sqP)[20]  = (float(*)[20])(smem + 148608);                     // 640 B

  const int tid = threadIdx.x, lane = tid & 63, wv = tid >> 6;  // wv 0..7
  const int b0 = bt * 16;
  const int arow = lane & 15, koff = (lane >> 4) * 8, crow0 = (lane >> 4) * 4;
  const int colr0 = 32 * wv + (lane & 15), colr1 = colr0 + 16;
  const int nt0 = 2 * wv, nt1 = 2 * wv + 1, nt2 = 16 + 2 * wv, nt3 = 17 + 2 * wv;

  // cand weights -> LDS (one-time)
  for (int i = tid; i < 8192; i += 512)
    *reinterpret_cast<bf16x8*>(&wc_s[i * 8]) = *reinterpret_cast<const bf16x8*>(&cfrag[i * 8]);

  // gate weights -> AGPR (128 regs), pinned each iteration
  bf16x8 wgr0[8], wgr1[8], wgr2[8], wgr3[8];
#pragma unroll
  for (int kc = 0; kc < 8; ++kc) {
    wgr0[kc] = *reinterpret_cast<const bf16x8*>(&gfrag[((nt0 * 8 + kc) * 64 + lane) * 8]);
    wgr1[kc] = *reinterpret_cast<const bf16x8*>(&gfrag[((nt1 * 8 + kc) * 64 + lane) * 8]);
    wgr2[kc] = *reinterpret_cast<const bf16x8*>(&gfrag[((nt2 * 8 + kc) * 64 + lane) * 8]);
    wgr3[kc] = *reinterpret_cast<const bf16x8*>(&gfrag[((nt3 * 8 + kc) * 64 + lane) * 8]);
  }

  const float gw_r0 = gnw[colr0], gb_r0 = gnb[colr0];
  const float gw_r1 = gnw[colr1], gb_r1 = gnb[colr1];
  const float gw_z0 = gnw[256 + colr0], gb_z0 = gnb[256 + colr0];
  const float gw_z1 = gnw[256 + colr1], gb_z1 = gnb[256 + colr1];
  const float cw0 = cnw[colr0], cb0 = cnb[colr0];
  const float cw1 = cnw[colr1], cb1 = cnb[colr1];

  float hm[2][4];
  if (first) {
#pragma unroll
    for (int g = 0; g < 4; ++g) { hm[0][g] = 0.f; hm[1][g] = 0.f; }
    for (int i = tid; i < 16 * 264; i += 512) (&h_s[0][0])[i] = 0;
  } else {
#pragma unroll
    for (int g = 0; g < 4; ++g) {
      hm[0][g] = hstate[(size_t)(b0 + crow0 + g) * 256 + colr0];
      hm[1][g] = hstate[(size_t)(b0 + crow0 + g) * 256 + colr1];
    }
    int r = tid >> 5, c8 = (tid & 31) * 8;
    float4 v0 = *reinterpret_cast<const float4*>(&hstate[(size_t)(b0 + r) * 256 + c8]);
    float4 v1 = *reinterpret_cast<const float4*>(&hstate[(size_t)(b0 + r) * 256 + c8 + 4]);
    ushort4 o0, o1;
    o0.x = f2bf(v0.x); o0.y = f2bf(v0.y); o0.z = f2bf(v0.z); o0.w = f2bf(v0.w);
    o1.x = f2bf(v1.x); o1.y = f2bf(v1.y); o1.z = f2bf(v1.z); o1.w = f2bf(v1.w);
    *reinterpret_cast<ushort4*>(&h_s[r][c8]) = o0;
    *reinterpret_cast<ushort4*>(&h_s[r][c8 + 4]) = o1;
  }
  __syncthreads();

  const unsigned short* Pr = Pc + ((size_t)bt * TC * 768 + colr0) * 16;
  // prefetch step 0
  ushort4 npr0 = *reinterpret_cast<const ushort4*>(Pr + crow0);
  ushort4 npr1 = *reinterpret_cast<const ushort4*>(Pr + 256 + crow0);
  ushort4 npz0 = *reinterpret_cast<const ushort4*>(Pr + 4096 + crow0);
  ushort4 npz1 = *reinterpret_cast<const ushort4*>(Pr + 4352 + crow0);
  ushort4 npn0 = *reinterpret_cast<const ushort4*>(Pr + 8192 + crow0);
  ushort4 npn1 = *reinterpret_cast<const ushort4*>(Pr + 8448 + crow0);

  for (int tt = 0; tt < TC; ++tt) {
    PIN8A(wgr0); PIN8A(wgr1); PIN8A(wgr2); PIN8A(wgr3);

    ushort4 pr0 = npr0, pr1 = npr1, pz0 = npz0, pz1 = npz1, pn0 = npn0, pn1 = npn1;
    if (tt + 1 < TC) {   // prefetch next step's P (hidden under this step)
      Pr += 12288;
      npr0 = *reinterpret_cast<const ushort4*>(Pr + crow0);
      npr1 = *reinterpret_cast<const ushort4*>(Pr + 256 + crow0);
      npz0 = *reinterpret_cast<const ushort4*>(Pr + 4096 + crow0);
      npz1 = *reinterpret_cast<const ushort4*>(Pr + 4352 + crow0);
      npn0 = *reinterpret_cast<const ushort4*>(Pr + 8192 + crow0);
      npn1 = *reinterpret_cast<const ushort4*>(Pr + 8448 + crow0);
    }

    // ---- gates MFMA (AGPR weights) ----
    f32x4 a0 = {0, 0, 0, 0}, a1 = {0, 0, 0, 0}, a2 = {0, 0, 0, 0}, a3 = {0, 0, 0, 0};
#pragma unroll
    for (int kc = 0; kc < 8; ++kc) {
      bf16x8 av = *reinterpret_cast<const bf16x8*>(&h_s[arow][kc * 32 + koff]);
      a0 = __builtin_amdgcn_mfma_f32_16x16x32_bf16(av, wgr0[kc], a0, 0, 0, 0);
      a1 = __builtin_amdgcn_mfma_f32_16x16x32_bf16(av, wgr1[kc], a1, 0, 0, 0);
      a2 = __builtin_amdgcn_mfma_f32_16x16x32_bf16(av, wgr2[kc], a2, 0, 0, 0);
      a3 = __builtin_amdgcn_mfma_f32_16x16x32_bf16(av, wgr3[kc], a3, 0, 0, 0);
    }
    float vr0[4], vr1[4], vz0[4], vz1[4];
    {
      float s4[4], q4[4];
#pragma unroll
      for (int g = 0; g < 4; ++g) {
        vr0[g] = a0[g] + bfh(((const unsigned short*)&pr0)[g]);
        vr1[g] = a1[g] + bfh(((const unsigned short*)&pr1)[g]);
        vz0[g] = a2[g] + bfh(((const unsigned short*)&pz0)[g]);
        vz1[g] = a3[g] + bfh(((const unsigned short*)&pz1)[g]);
        s4[g] = red16(vr0[g] + vr1[g] + vz0[g] + vz1[g]);
        q4[g] = red16(vr0[g] * vr0[g] + vr1[g] * vr1[g] + vz0[g] * vz0[g] + vz1[g] * vz1[g]);
      }
      if ((lane & 15) == 0) {
        *reinterpret_cast<f32x4*>(&sumP[wv][crow0]) = (f32x4){s4[0], s4[1], s4[2], s4[3]};
        *reinterpret_cast<f32x4*>(&sqP[wv][crow0])  = (f32x4){q4[0], q4[1], q4[2], q4[3]};
      }
    }
    __syncthreads();                                   // B1

    // ---- gate LN stats (shfl broadcast) + apply ----
    float zf[2][4];
    {
      int sg = lane >> 4, rr = lane & 15;
      float S = sumP[2 * sg][rr] + sumP[2 * sg + 1][rr];
      float Q = sqP[2 * sg][rr] + sqP[2 * sg + 1][rr];
      S += __shfl_xor(S, 16, 64); Q += __shfl_xor(Q, 16, 64);
      S += __shfl_xor(S, 32, 64); Q += __shfl_xor(Q, 32, 64);
      float mn = S * (1.f / 512.f);
      float rs = __builtin_amdgcn_rsqf(Q * (1.f / 512.f) - mn * mn + EPS_);
#pragma unroll
      for (int g = 0; g < 4; ++g) {
        float m_ = __shfl(mn, crow0 + g, 64);
        float r_ = __shfl(rs, crow0 + g, 64);
        float rv0 = sigm_(fmaf((vr0[g] - m_) * r_, gw_r0, gb_r0));
        float rv1 = sigm_(fmaf((vr1[g] - m_) * r_, gw_r1, gb_r1));
        zf[0][g]  = sigm_(fmaf((vz0[g] - m_) * r_, gw_z0, gb_z0));
        zf[1][g]  = sigm_(fmaf((vz1[g] - m_) * r_, gw_z1, gb_z1));
        rh_s[crow0 + g][colr0] = f2bf(rv0 * hm[0][g]);
        rh_s[crow0 + g][colr1] = f2bf(rv1 * hm[1][g]);
      }
    }
    __syncthreads();                                   // B2

    // ---- cand MFMA (LDS weights) ----
    f32x4 c0a = {0, 0, 0, 0}, c1a = {0, 0, 0, 0};
#pragma unroll
    for (int kc = 0; kc < 8; ++kc) {
      bf16x8 av = *reinterpret_cast<const bf16x8*>(&rh_s[arow][kc * 32 + koff]);
      bf16x8 b0v = *reinterpret_cast<const bf16x8*>(&wc_s[((nt0 * 8 + kc) * 64 + lane) * 8]);
      bf16x8 b1v = *reinterpret_cast<const bf16x8*>(&wc_s[((nt1 * 8 + kc) * 64 + lane) * 8]);
      c0a = __builtin_amdgcn_mfma_f32_16x16x32_bf16(av, b0v, c0a, 0, 0, 0);
      c1a = __builtin_amdgcn_mfma_f32_16x16x32_bf16(av, b1v, c1a, 0, 0, 0);
    }
    float vc0[4], vc1[4];
    {
      float s4[4], q4[4];
#pragma unroll
      for (int g = 0; g < 4; ++g) {
        vc0[g] = c0a[g] + bfh(((const unsigned short*)&pn0)[g]);
        vc1[g] = c1a[g] + bfh(((const unsigned short*)&pn1)[g]);
        s4[g] = red16(vc0[g] + vc1[g]);
        q4[g] = red16(vc0[g] * vc0[g] + vc1[g] * vc1[g]);
      }
      if ((lane & 15) == 0) {
        *reinterpret_cast<f32x4*>(&sumP[wv][crow0]) = (f32x4){s4[0], s4[1], s4[2], s4[3]};
        *reinterpret_cast<f32x4*>(&sqP[wv][crow0])  = (f32x4){q4[0], q4[1], q4[2], q4[3]};
      }
    }
    __syncthreads();                                   // B3

    // ---- cand LN (shfl broadcast) + tanh + h update ----
    {
      int sg = lane >> 4, rr = lane & 15;
      float S = sumP[2 * sg][rr] + sumP[2 * sg + 1][rr];
      float Q = sqP[2 * sg][rr] + sqP[2 * sg + 1][rr];
      S += __shfl_xor(S, 16, 64); Q += __shfl_xor(Q, 16, 64);
      S += __shfl_xor(S, 32, 64); Q += __shfl_xor(Q, 32, 64);
      float mn = S * (1.f / 256.f);
      float rs = __builtin_amdgcn_rsqf(Q * (1.f / 256.f) - mn * mn + EPS_);
      unsigned short* hrow = h0out ? (h0out + (size_t)(bt * TC + tt) * 4096) : (unsigned short*)nullptr;
#pragma unroll
      for (int g = 0; g < 4; ++g) {
        float m_ = __shfl(mn, crow0 + g, 64);
        float r_ = __shfl(rs, crow0 + g, 64);
        float n0 = tanh_(fmaf((vc0[g] - m_) * r_, cw0, cb0));
        float n1 = tanh_(fmaf((vc1[g] - m_) * r_, cw1, cb1));
        float h0n = fmaf(zf[0][g], n0 - hm[0][g], hm[0][g]);
        float h1n = fmaf(zf[1][g], n1 - hm[1][g], hm[1][g]);
        hm[0][g] = h0n; hm[1][g] = h1n;
        unsigned short hb0 = f2bf(h0n), hb1 = f2bf(h1n);
        h_s[crow0 + g][colr0] = hb0;
        h_s[crow0 + g][colr1] = hb1;
        if (hrow) {
          hrow[(size_t)(crow0 + g) * 256 + colr0] = hb0;
          hrow[(size_t)(crow0 + g) * 256 + colr1] = hb1;
        }
      }
    }
    __syncthreads();                                   // B4
  }

#pragma unroll
  for (int g = 0; g < 4; ++g) {
    hstate[(size_t)(b0 + crow0 + g) * 256 + colr0] = hm[0][g];
    hstate[(size_t)(b0 + crow0 + g) * 256 + colr1] = hm[1][g];
  }
}

// ------------------------------- mega kernel ---------------------------------
__launch_bounds__(512, 2)
__global__ void mega(
    const float* __restrict__ x,
    const unsigned short* __restrict__ g0h, const unsigned short* __restrict__ c0h,
    const unsigned short* __restrict__ g1h, const unsigned short* __restrict__ c1h,
    const unsigned short* __restrict__ wx0, const unsigned short* __restrict__ wx1,
    const float* __restrict__ b768_0, const float* __restrict__ b768_1,
    const float* __restrict__ gnw0, const float* __restrict__ gnb0,
    const float* __restrict__ cnw0, const float* __restrict__ cnb0,
    const float* __restrict__ gnw1, const float* __restrict__ gnb1,
    const float* __restrict__ cnw1, const float* __restrict__ cnb1,
    float* __restrict__ hst0, float* __restrict__ hst1,
    unsigned short* __restrict__ P0a, unsigned short* __restrict__ P0b,
    unsigned short* __restrict__ P1a, unsigned short* __restrict__ P1b,
    unsigned short* __restrict__ h0a, unsigned short* __restrict__ h0b,
    int k, int TC, int NC)
{
  __shared__ __align__(16) unsigned char smem[149504];
  const int bid = blockIdx.x;

  if (bid < 32) {                       // ---- B: layer-0 chunk k ----
    if (k >= NC) return;
    unsigned short* P0 = (k & 1) ? P0b : P0a;
    unsigned short* h0 = (k & 1) ? h0b : h0a;
    gru_body(smem, bid, g0h, c0h, P0, gnw0, gnb0, cnw0, cnb0, hst0, h0, TC, k == 0);
  } else if (bid < 64) {                // ---- D: layer-1 chunk k-2 ----
    int kD = k - 2;
    if (kD < 0 || kD >= NC) return;
    unsigned short* P1 = (kD & 1) ? P1b : P1a;
    gru_body(smem, bid - 32, g1h, c1h, P1, gnw1, gnb1, cnw1, cnb1, hst1,
             (unsigned short*)nullptr, TC, kD == 0);
  } else if (bid < 160) {               // ---- A: precomp P0 chunk k+1 ----
    int kA = k + 1;
    if (kA >= NC) return;
    unsigned short* P0 = (kA & 1) ? P0b : P0a;
    int team = (bid - 64) * 2 + (threadIdx.x >> 8);
    int t256 = threadIdx.x & 255;
    unsigned short* A_s = (unsigned short*)(smem + (threadIdx.x >> 8) * 32768);
    unsigned short* B_s = A_s + 8192;
    int ntile = 24 * TC;                // (4*TC m-tiles) x 6 n-tiles
    for (int i = team; i < ntile; i += 192) {
      int mi = i % (4 * TC), ni = i / (4 * TC);
      precomp_tile(x, wx0, b768_0, P0, TC, kA * TC, 64, 1, mi, ni * 128, A_s, B_s, t256);
    }
  } else {                              // ---- C: precomp P1 chunk k-1 ----
    int kC = k - 1;
    if (kC < 0 || kC >= NC) return;
    const unsigned short* h0 = (kC & 1) ? h0b : h0a;
    unsigned short* P1 = (kC & 1) ? P1b : P1a;
    int team = (bid - 160) * 2 + (threadIdx.x >> 8);
    int t256 = threadIdx.x & 255;
    unsigned short* A_s = (unsigned short*)(smem + (threadIdx.x >> 8) * 32768);
    unsigned short* B_s = A_s + 8192;
    int ntile = 24 * TC;
    for (int i = team; i < ntile; i += 192) {
      int mi = i % (4 * TC), ni = i / (4 * TC);
      precomp_tile(h0, wx1, b768_1, P1, TC, 0, 256, 0, mi, ni * 128, A_s, B_s, t256);
    }
  }
}

// ------------------------------- FC head -------------------------------------
__launch_bounds__(256)
__global__ void head_k(const float* __restrict__ h1, const float* __restrict__ fcW,
                       const float* __restrict__ fcb, float* __restrict__ out) {
  __shared__ float hs[16][256];
  const int tid = threadIdx.x, b0 = blockIdx.x * 16;
  for (int i = tid; i < 16 * 64; i += 256) {
    int r = i >> 6, c4 = (i & 63) * 4;
    *reinterpret_cast<float4*>(&hs[r][c4]) =
        *reinterpret_cast<const float4*>(&h1[(size_t)(b0 + r) * 256 + c4]);
  }
  __syncthreads();
  int r = tid >> 4, o = (tid & 15) * 4;
  float a0 = fcb[o], a1 = fcb[o + 1], a2 = fcb[o + 2], a3 = fcb[o + 3];
  for (int k = 0; k < 256; ++k) {
    float h = hs[r][k];
    a0 = fmaf(h, fcW[(size_t)(o + 0) * 256 + k], a0);
    a1 = fmaf(h, fcW[(size_t)(o + 1) * 256 + k], a1);
    a2 = fmaf(h, fcW[(size_t)(o + 2) * 256 + k], a2);
    a3 = fmaf(h, fcW[(size_t)(o + 3) * 256 + k], a3);
  }
  float4 ov = {a0, a1, a2, a3};
  *reinterpret_cast<float4*>(&out[(size_t)(b0 + r) * 64 + o]) = ov;
}

// --------------------------------- host --------------------------------------
extern "C" void kernel_launch(void* const* d_in, const int* in_sizes, int n_in,
                              void* d_out, int out_size, void* d_ws, size_t ws_size,
                              hipStream_t stream) {
  (void)in_sizes; (void)n_in; (void)out_size;
  const float* x    = (const float*)d_in[0];
  const float* Wg0  = (const float*)d_in[1];
  const float* bg0  = (const float*)d_in[2];
  const float* gnw0 = (const float*)d_in[3];
  const float* gnb0 = (const float*)d_in[4];
  const float* Wc0  = (const float*)d_in[5];
  const float* bc0  = (const float*)d_in[6];
  const float* cnw0 = (const float*)d_in[7];
  const float* cnb0 = (const float*)d_in[8];
  const float* Wg1  = (const float*)d_in[9];
  const float* bg1  = (const float*)d_in[10];
  const float* gnw1 = (const float*)d_in[11];
  const float* gnb1 = (const float*)d_in[12];
  const float* Wc1  = (const float*)d_in[13];
  const float* bc1  = (const float*)d_in[14];
  const float* cnw1 = (const float*)d_in[15];
  const float* cnb1 = (const float*)d_in[16];
  const float* fcW  = (const float*)d_in[17];
  const float* fcb  = (const float*)d_in[18];

  float* hst0 = (float*)d_ws;                 // 512*256 fp32
  float* hst1 = hst0 + 131072;
  float* b768_0 = hst1 + 131072;
  float* b768_1 = b768_0 + 768;
  unsigned short* g0h = (unsigned short*)(b768_1 + 768);
  unsigned short* c0h = g0h + 131072;
  unsigned short* g1h = c0h + 65536;
  unsigned short* c1h = g1h + 131072;
  unsigned short* wx0 = c1h + 65536;
  unsigned short* wx1 = wx0 + 49152;
  unsigned short* dynbase = wx1 + 196608;

  const size_t fixed_bytes = (size_t)((char*)dynbase - (char*)d_ws);
  int TC = 32;
  while (TC > 4) {
    size_t need = fixed_bytes + (size_t)TC * 3670016;  // 2x(P0+P1) + 2x h0
    if (need <= ws_size) break;
    TC >>= 1;
  }
  const int NC = T_ / TC;

  unsigned short* P0a = dynbase;
  unsigned short* P0b = P0a + (size_t)TC * 393216;
  unsigned short* P1a = P0b + (size_t)TC * 393216;
  unsigned short* P1b = P1a + (size_t)TC * 393216;
  unsigned short* h0a = P1b + (size_t)TC * 393216;
  unsigned short* h0b = h0a + (size_t)TC * 131072;

  prep_frag<<<512, 256, 0, stream>>>(Wg0, g0h, 512, 320, 64);
  prep_frag<<<256, 256, 0, stream>>>(Wc0, c0h, 256, 320, 64);
  prep_frag<<<512, 256, 0, stream>>>(Wg1, g1h, 512, 512, 256);
  prep_frag<<<256, 256, 0, stream>>>(Wc1, c1h, 256, 512, 256);
  prep_wx<<<192, 256, 0, stream>>>(Wg0, Wc0, wx0, 64, 320, 320);
  prep_wx<<<768, 256, 0, stream>>>(Wg1, Wc1, wx1, 256, 512, 512);
  bias_cat<<<3, 256, 0, stream>>>(bg0, bc0, b768_0);
  bias_cat<<<3, 256, 0, stream>>>(bg1, bc1, b768_1);

  // prologue: A(0) -> P0a
  precomp_std<<<dim3(4 * TC, 6), 256, 0, stream>>>(x, wx0, b768_0, P0a, TC, 0, 64, 1);

  for (int k = 0; k < NC + 2; ++k) {
    mega<<<256, 512, 0, stream>>>(x, g0h, c0h, g1h, c1h, wx0, wx1, b768_0, b768_1,
        gnw0, gnb0, cnw0, cnb0, gnw1, gnb1, cnw1, cnb1,
        hst0, hst1, P0a, P0b, P1a, P1b, h0a, h0b, k, TC, NC);
  }

  head_k<<<32, 256, 0, stream>>>(hst1, fcW, fcb, (float*)d_out);
}